// Round 1
// baseline (59565.918 us; speedup 1.0000x reference)
//
#include <hip/hip_runtime.h>
#include <math.h>

#define HH 160
#define WW 180
#define HWSZ (HH*WW)
#define BB 8

// ---------------- activation (eq. 33 smoothed ReLU), delta = 0.01 ----------------
__device__ __forceinline__ float actf(float x) {
  float q = x*x*25.0f + 0.5f*x + 0.0025f;       // x^2/(4d) + x/2 + d/4
  float r = fmaxf(x, 0.0f);
  return (fabsf(x) > 0.01f) ? r : q;
}
__device__ __forceinline__ float actdf(float x) {
  float q = x*50.0f + 0.5f;                      // x/(2d) + 1/2
  float r = (x > 0.0f) ? 1.0f : 0.0f;
  return (fabsf(x) > 0.01f) ? r : q;
}

// ---------------- complex 3x3 SAME conv, direct, per-thread all-COUT accumulation ----
// MODE: 0 = plain, 1 = apply act, 2 = multiply by complex act-derivative of der buffer
// TRANSP: use swapped-io + spatially flipped weights (conv_transpose2d stride1 pad1)
template<int CIN, int COUT, bool TRANSP, int MODE>
__global__ __launch_bounds__(256)
void conv_kernel(const float* __restrict__ inR, const float* __restrict__ inI,
                 const float* __restrict__ wR, const float* __restrict__ wI,
                 float* __restrict__ outR, float* __restrict__ outI,
                 const float* __restrict__ derR, const float* __restrict__ derI)
{
  constexpr int CHUNK = (CIN >= 8) ? 8 : CIN;
  __shared__ float smR[CHUNK][10][34];
  __shared__ float smI[CHUNK][10][34];

  const int tx = threadIdx.x & 31;
  const int ty = threadIdx.x >> 5;
  const int x0 = blockIdx.x * 32;
  const int y0 = blockIdx.y * 8;
  const int b  = blockIdx.z;
  const int gx = x0 + tx, gy = y0 + ty;

  float accR[COUT], accI[COUT];
#pragma unroll
  for (int o = 0; o < COUT; ++o) { accR[o] = 0.f; accI[o] = 0.f; }

  for (int c0 = 0; c0 < CIN; c0 += CHUNK) {
    // cooperative halo load: rows [y0-1, y0+9), cols [x0-1, x0+33), zero-padded
    for (int idx = threadIdx.x; idx < CHUNK*340; idx += 256) {
      int cc = idx / 340;
      int rem = idx - cc*340;
      int yy = rem / 34;
      int xx = rem - yy*34;
      int sy = y0 + yy - 1, sx = x0 + xx - 1;
      float vR = 0.f, vI = 0.f;
      if (sy >= 0 && sy < HH && sx >= 0 && sx < WW) {
        int o2 = ((b*CIN + (c0+cc))*HH + sy)*WW + sx;
        vR = inR[o2]; vI = inI[o2];
      }
      smR[cc][yy][xx] = vR; smI[cc][yy][xx] = vI;
    }
    __syncthreads();

#pragma unroll 1
    for (int cc = 0; cc < CHUNK; ++cc) {
      const int c = c0 + cc;
#pragma unroll
      for (int tap = 0; tap < 9; ++tap) {
        const int ky = tap / 3, kx = tap - ky*3;
        float ar = smR[cc][ty+ky][tx+kx];
        float ai = smI[cc][ty+ky][tx+kx];
#pragma unroll
        for (int o = 0; o < COUT; ++o) {
          // weights stay in ORIGINAL conv layout; transposed indexes [c][o] flipped taps
          int widx = TRANSP ? ((c*COUT + o)*9 + (8 - tap))
                            : ((o*CIN  + c)*9 + tap);
          float wr = wR[widx], wi = wI[widx];
          accR[o] += ar*wr - ai*wi;
          accI[o] += ar*wi + ai*wr;
        }
      }
    }
    __syncthreads();
  }

  if (gx < WW && gy < HH) {
#pragma unroll
    for (int o = 0; o < COUT; ++o) {
      int off = ((b*COUT + o)*HH + gy)*WW + gx;
      float pr = accR[o], pi = accI[o];
      if constexpr (MODE == 1) { pr = actf(pr); pi = actf(pi); }
      if constexpr (MODE == 2) {
        float dr = actdf(derR[off]);
        float di = actdf(derI[off]);
        float nr = pr*dr - pi*di;
        float ni = pr*di + pi*dr;
        pr = nr; pi = ni;
      }
      outR[off] = pr; outI[off] = pi;
    }
  }
}

// ---------------- channel-norm normalize: g = w4 / max(||w4||_ch, thr) ----------------
__global__ void normalize_kernel(float* __restrict__ gR, float* __restrict__ gI,
                                 const float* __restrict__ thr_p)
{
  int i = blockIdx.x*256 + threadIdx.x;
  if (i >= BB*HWSZ) return;
  int b = i / HWSZ, p = i - b*HWSZ;
  float thr = thr_p[0];     // * GAMMA (=1.0)
  size_t base = (size_t)b*32*HWSZ + p;
  float s = 0.f;
#pragma unroll
  for (int c = 0; c < 32; ++c) {
    float vr = gR[base + (size_t)c*HWSZ], vi = gI[base + (size_t)c*HWSZ];
    s += vr*vr + vi*vi;
  }
  float inv = 1.0f / fmaxf(sqrtf(s), thr);
#pragma unroll
  for (int c = 0; c < 32; ++c) {
    gR[base + (size_t)c*HWSZ] *= inv;
    gI[base + (size_t)c*HWSZ] *= inv;
  }
}

// ---------------- DFT-by-matmul machinery ----------------
__global__ void gen_dft(float2* __restrict__ M, int N, double sign, double scale) {
  int idx = blockIdx.x*256 + threadIdx.x;
  if (idx >= N*N) return;
  int r = idx / N, c = idx - r*N;
  long m = ((long)r * (long)c) % N;
  double a = sign * 2.0 * 3.14159265358979323846 * (double)m / (double)N;
  M[idx] = make_float2((float)(cos(a)*scale), (float)(sin(a)*scale));
}

// out[b,h,v] = sum_w in[b,h,w] * M[w,v]  (input as separate re/im planes)
__global__ void dft_row_planes(const float* __restrict__ xR, const float* __restrict__ xI,
                               float2* __restrict__ out, const float2* __restrict__ M) {
  int bh = blockIdx.x;
  int v = threadIdx.x; if (v >= WW) return;
  const float* rowR = xR + (size_t)bh*WW;
  const float* rowI = xI + (size_t)bh*WW;
  float ar = 0.f, ai = 0.f;
  for (int w = 0; w < WW; ++w) {
    float sr = rowR[w], si = rowI[w];
    float2 m = M[w*WW + v];
    ar += sr*m.x - si*m.y;
    ai += sr*m.y + si*m.x;
  }
  out[(size_t)bh*WW + v] = make_float2(ar, ai);
}

__global__ void dft_row_c(const float2* __restrict__ in, float2* __restrict__ out,
                          const float2* __restrict__ M) {
  int bh = blockIdx.x;
  int v = threadIdx.x; if (v >= WW) return;
  const float2* row = in + (size_t)bh*WW;
  float ar = 0.f, ai = 0.f;
  for (int w = 0; w < WW; ++w) {
    float2 s = row[w];
    float2 m = M[w*WW + v];
    ar += s.x*m.x - s.y*m.y;
    ai += s.x*m.y + s.y*m.x;
  }
  out[(size_t)bh*WW + v] = make_float2(ar, ai);
}

// out[b,u,v] = sum_h M[u,h] * in[b,h,v]
__global__ void dft_col_c(const float2* __restrict__ in, float2* __restrict__ out,
                          const float2* __restrict__ M) {
  int bu = blockIdx.x;
  int v = threadIdx.x; if (v >= WW) return;
  int b = bu / HH, u = bu - b*HH;
  const float2* base = in + (size_t)b*HWSZ;
  float ar = 0.f, ai = 0.f;
  for (int h = 0; h < HH; ++h) {
    float2 m = M[u*HH + h];
    float2 s = base[(size_t)h*WW + v];
    ar += s.x*m.x - s.y*m.y;
    ai += s.x*m.y + s.y*m.x;
  }
  out[(size_t)bu*WW + v] = make_float2(ar, ai);
}

// ---------------- small pointwise kernels ----------------
__global__ void mask2_kernel(float2* __restrict__ t, const float* __restrict__ mask) {
  int i = blockIdx.x*256 + threadIdx.x;
  if (i >= BB*HWSZ) return;
  float m = mask[i % HWSZ]; float mm = m*m;
  float2 v = t[i];
  t[i] = make_float2(v.x*mm, v.y*mm);
}

__global__ void maskk_kernel(const float* __restrict__ k, const float* __restrict__ mask,
                             float2* __restrict__ t) {
  int i = blockIdx.x*256 + threadIdx.x;
  if (i >= BB*HWSZ) return;
  int b = i / HWSZ, p = i - b*HWSZ;
  float m = mask[p];
  t[i] = make_float2(m * k[(size_t)b*2*HWSZ + p], m * k[(size_t)b*2*HWSZ + HWSZ + p]);
}

__global__ void unpack_kernel(const float* __restrict__ x, float* __restrict__ xr,
                              float* __restrict__ xi) {
  int i = blockIdx.x*256 + threadIdx.x;
  if (i >= BB*HWSZ) return;
  int b = i / HWSZ, p = i - b*HWSZ;
  xr[i] = x[(size_t)b*2*HWSZ + p];
  xi[i] = x[(size_t)b*2*HWSZ + HWSZ + p];
}

__global__ void update_kernel(float* __restrict__ xr, float* __restrict__ xi,
                              const float2* __restrict__ gradf, const float2* __restrict__ cterm,
                              const float* __restrict__ grR, const float* __restrict__ grI,
                              const float* __restrict__ alphas, const float* __restrict__ betas,
                              int phase) {
  int i = blockIdx.x*256 + threadIdx.x;
  if (i >= BB*HWSZ) return;
  float a = alphas[phase], bb = betas[phase];
  float gfr = gradf[i].x - cterm[i].x;
  float gfi = gradf[i].y - cterm[i].y;
  xr[i] -= a*gfr + bb*grR[i];
  xi[i] -= a*gfi + bb*grI[i];
}

__global__ void pack_kernel(const float* __restrict__ x1r, const float* __restrict__ x1i,
                            const float* __restrict__ x2r, const float* __restrict__ x2i,
                            float* __restrict__ out) {
  int i = blockIdx.x*256 + threadIdx.x;
  if (i >= BB*HWSZ) return;
  int b = i / HWSZ, p = i - b*HWSZ;
  size_t ob = (size_t)b*4*HWSZ;
  out[ob + p]          = x1r[i];
  out[ob + HWSZ + p]   = x1i[i];
  out[ob + 2*HWSZ + p] = x2r[i];
  out[ob + 3*HWSZ + p] = x2i[i];
}

// ---------------- launch ----------------
extern "C" void kernel_launch(void* const* d_in, const int* in_sizes, int n_in,
                              void* d_out, int out_size, void* d_ws, size_t ws_size,
                              hipStream_t stream) {
  (void)in_sizes; (void)n_in; (void)out_size; (void)ws_size;
  const float* x1in = (const float*)d_in[0];
  const float* x2in = (const float*)d_in[1];
  const float* k1   = (const float*)d_in[2];
  const float* k2   = (const float*)d_in[3];
  const float* mask = (const float*)d_in[4];
  const float* cw[16];
  for (int i = 0; i < 16; ++i) cw[i] = (const float*)d_in[5+i];
  const float* thr1 = (const float*)d_in[21];
  const float* thr2 = (const float*)d_in[22];
  const float* al1  = (const float*)d_in[23];
  const float* al2  = (const float*)d_in[24];
  const float* be1  = (const float*)d_in[25];
  const float* be2  = (const float*)d_in[26];
  float* out = (float*)d_out;

  const size_t P32 = (size_t)BB*32*HWSZ;
  const size_t P1  = (size_t)BB*HWSZ;
  float* ws = (float*)d_ws;
  size_t off = 0;
  float* act1 = ws + off; off += 2*P32;
  float* act2 = ws + off; off += 2*P32;
  float* act3 = ws + off; off += 2*P32;
  float* w4b  = ws + off; off += 2*P32;
  float* x1p  = ws + off; off += 2*P1;
  float* x2p  = ws + off; off += 2*P1;
  float* grp  = ws + off; off += 2*P1;
  float2* t1  = (float2*)(ws + off); off += 2*P1;
  float2* t2  = (float2*)(ws + off); off += 2*P1;
  float2* gf  = (float2*)(ws + off); off += 2*P1;
  float2* ct1 = (float2*)(ws + off); off += 2*P1;
  float2* ct2 = (float2*)(ws + off); off += 2*P1;
  float2* EWf = (float2*)(ws + off); off += 2*(size_t)WW*WW;
  float2* EWi = (float2*)(ws + off); off += 2*(size_t)WW*WW;
  float2* EHf = (float2*)(ws + off); off += 2*(size_t)HH*HH;
  float2* EHi = (float2*)(ws + off); off += 2*(size_t)HH*HH;

  const dim3 CG((WW+31)/32, (HH+7)/8, BB);   // conv grid: 6 x 20 x 8
  const dim3 CB(256);
  const int NP1 = (BB*HWSZ + 255)/256;       // pointwise grid over B*H*W
  const int DFTG = BB*HH;                    // dft grid (one block per (b,row/col))
  const int DFTB = 192;                      // >= 180, multiple of 64

  // twiddle matrices
  gen_dft<<<(WW*WW+255)/256, 256, 0, stream>>>(EWf, WW, -1.0, 1.0);
  gen_dft<<<(WW*WW+255)/256, 256, 0, stream>>>(EWi, WW,  1.0, 1.0/(double)WW);
  gen_dft<<<(HH*HH+255)/256, 256, 0, stream>>>(EHf, HH, -1.0, 1.0);
  gen_dft<<<(HH*HH+255)/256, 256, 0, stream>>>(EHi, HH,  1.0, 1.0/(double)HH);

  // unpack x into planes
  unpack_kernel<<<NP1, 256, 0, stream>>>(x1in, x1p, x1p + P1);
  unpack_kernel<<<NP1, 256, 0, stream>>>(x2in, x2p, x2p + P1);

  // cterm = ifft2(mask * k)   (phase-invariant)
  maskk_kernel<<<NP1, 256, 0, stream>>>(k1, mask, t1);
  dft_col_c<<<DFTG, DFTB, 0, stream>>>(t1, t2, EHi);
  dft_row_c<<<DFTG, DFTB, 0, stream>>>(t2, ct1, EWi);
  maskk_kernel<<<NP1, 256, 0, stream>>>(k2, mask, t1);
  dft_col_c<<<DFTG, DFTB, 0, stream>>>(t1, t2, EHi);
  dft_row_c<<<DFTG, DFTB, 0, stream>>>(t2, ct2, EWi);

  auto run_gradr = [&](float* xp, const float* const* c, const float* thrp) {
    // forward CNN
    conv_kernel<1,32,false,1><<<CG, CB, 0, stream>>>(xp, xp+P1, c[0], c[1],
                                                     act1, act1+P32, nullptr, nullptr);
    conv_kernel<32,32,false,1><<<CG, CB, 0, stream>>>(act1, act1+P32, c[2], c[3],
                                                      act2, act2+P32, nullptr, nullptr);
    conv_kernel<32,32,false,1><<<CG, CB, 0, stream>>>(act2, act2+P32, c[4], c[5],
                                                      act3, act3+P32, nullptr, nullptr);
    conv_kernel<32,32,false,0><<<CG, CB, 0, stream>>>(act3, act3+P32, c[6], c[7],
                                                      w4b, w4b+P32, nullptr, nullptr);
    normalize_kernel<<<NP1, 256, 0, stream>>>(w4b, w4b+P32, thrp);
    // backward: convT fused with act-derivative complex multiply (writes over the
    // act buffer it reads pointwise — same-element only, race-free)
    conv_kernel<32,32,true,2><<<CG, CB, 0, stream>>>(w4b, w4b+P32, c[6], c[7],
                                                     act3, act3+P32, act3, act3+P32);
    conv_kernel<32,32,true,2><<<CG, CB, 0, stream>>>(act3, act3+P32, c[4], c[5],
                                                     act2, act2+P32, act2, act2+P32);
    conv_kernel<32,32,true,2><<<CG, CB, 0, stream>>>(act2, act2+P32, c[2], c[3],
                                                     act1, act1+P32, act1, act1+P32);
    conv_kernel<32,1,true,0><<<CG, CB, 0, stream>>>(act1, act1+P32, c[0], c[1],
                                                    grp, grp+P1, nullptr, nullptr);
  };

  auto run_gradf = [&](float* xp) {
    dft_row_planes<<<DFTG, DFTB, 0, stream>>>(xp, xp+P1, t1, EWf);
    dft_col_c<<<DFTG, DFTB, 0, stream>>>(t1, t2, EHf);
    mask2_kernel<<<NP1, 256, 0, stream>>>(t2, mask);
    dft_col_c<<<DFTG, DFTB, 0, stream>>>(t2, t1, EHi);
    dft_row_c<<<DFTG, DFTB, 0, stream>>>(t1, gf, EWi);
  };

  const float* convsA[8] = {cw[0],cw[1],cw[2],cw[3],cw[4],cw[5],cw[6],cw[7]};
  const float* convsB[8] = {cw[8],cw[9],cw[10],cw[11],cw[12],cw[13],cw[14],cw[15]};

  for (int ph = 0; ph < 3; ++ph) {
    run_gradr(x1p, convsA, thr1);
    run_gradf(x1p);
    update_kernel<<<NP1, 256, 0, stream>>>(x1p, x1p+P1, gf, ct1, grp, grp+P1, al1, be1, ph);
    run_gradr(x2p, convsB, thr2);
    run_gradf(x2p);
    update_kernel<<<NP1, 256, 0, stream>>>(x2p, x2p+P1, gf, ct2, grp, grp+P1, al2, be2, ph);
  }

  pack_kernel<<<NP1, 256, 0, stream>>>(x1p, x1p+P1, x2p, x2p+P1, out);
}

// Round 4
// 9937.054 us; speedup vs baseline: 5.9943x; 5.9943x over previous
//
#include <hip/hip_runtime.h>
#include <math.h>

#define HH 160
#define WW 180
#define HWSZ (HH*WW)
#define BB 8
#define P1 ((size_t)BB*HWSZ)            // 230400
#define PE ((size_t)BB*32*HWSZ)         // 7372800 (one 32-ch plane set)

typedef unsigned short u16;
typedef __attribute__((ext_vector_type(8))) short short8;
typedef __attribute__((ext_vector_type(4))) float floatx4;

// ---------------- bf16 helpers ----------------
__device__ __forceinline__ u16 f2b(float f) {
  unsigned u = __builtin_bit_cast(unsigned, f);
  unsigned r = (u + 0x7fffu + ((u >> 16) & 1u)) >> 16;
  return (u16)r;
}
__device__ __forceinline__ float b2f(u16 h) {
  return __builtin_bit_cast(float, ((unsigned)h) << 16);
}

// ---------------- activation (eq. 33), delta = 0.01 ----------------
__device__ __forceinline__ float actf(float x) {
  float q = x*x*25.0f + 0.5f*x + 0.0025f;
  float r = fmaxf(x, 0.0f);
  return (fabsf(x) > 0.01f) ? r : q;
}
__device__ __forceinline__ float actdf(float x) {
  float q = x*50.0f + 0.5f;
  float r = (x > 0.0f) ? 1.0f : 0.0f;
  return (fabsf(x) > 0.01f) ? r : q;
}

// ---------------- weight prep: fp32 [o][c][9] -> bf16 [tap][nt][plane(r,i,-i)][o16][c32]
__global__ void prep_w3(const float* __restrict__ wr, const float* __restrict__ wi,
                        u16* __restrict__ dst, int bwd) {
  int idx = blockIdx.x*256 + threadIdx.x;
  if (idx >= 9*32*32) return;
  int tap = idx >> 10; int rem = idx & 1023; int o = rem >> 5; int c = rem & 31;
  int s = bwd ? ((c*32 + o)*9 + (8 - tap)) : ((o*32 + c)*9 + tap);
  float vr = wr[s], vi = wi[s];
  int nt = o >> 4, m = o & 15;
  size_t base = ((((size_t)tap*2 + nt)*3)*16 + (size_t)m)*32 + c;
  dst[base]        = f2b(vr);
  dst[base + 512]  = f2b(vi);
  dst[base + 1024] = f2b(-vi);
}

// ---------------- MFMA complex conv 32->32, 3x3 SAME, implicit GEMM -----------------
// in/out: bf16 planes, R at [0], I at [PE]. weights: prep_w3 layout.
// Tile: 16 wide x 4 high, 4 waves (one output row each). K = 32 channels per MFMA, 9 taps.
// MODE: 0 plain, 1 act, 2 complex-multiply by actdf(der planes)
template<int MODE>
__global__ __launch_bounds__(256)
void conv_mfma(const u16* __restrict__ inb, const u16* __restrict__ wb,
               u16* __restrict__ outb, const u16* __restrict__ derb)
{
  __shared__ u16 sm[6912];   // stage: [plane2][ch32][row6][col18]
  const int tid = threadIdx.x;
  const int x0 = blockIdx.x * 16, y0 = blockIdx.y * 4, b = blockIdx.z;

  // ---- stage input tile (rows y0-1..y0+4, cols x0-1..x0+16, 32 ch, R&I) ----
  for (int j = tid; j < 384; j += 256) {
    int plane = j / 192; int r2 = j - plane*192; int ch = r2 / 6; int row = r2 - ch*6;
    int gy = y0 - 1 + row;
    bool rowok = (gy >= 0) && (gy < HH);
    const u16* src = inb + (size_t)plane*PE + ((size_t)(b*32 + ch)*HH + (rowok ? gy : 0))*WW;
    u16* dst = &sm[plane*3456 + (ch*6 + row)*18];
    for (int col = 0; col < 18; ++col) {
      int gx = x0 - 1 + col;
      u16 v = 0;
      if (rowok && gx >= 0 && gx < WW) v = src[gx];
      dst[col] = v;
    }
  }
  __syncthreads();

  const int lane = tid & 63, w = tid >> 6;   // wave w -> output row y0+w
  const int m = lane & 15, q = lane >> 4;

  floatx4 accr[2] = {{0.f,0.f,0.f,0.f},{0.f,0.f,0.f,0.f}};
  floatx4 acci[2] = {{0.f,0.f,0.f,0.f},{0.f,0.f,0.f,0.f}};

#pragma unroll
  for (int tap = 0; tap < 9; ++tap) {
    const int ky = tap / 3, kx = tap - ky*3;
    // A fragment: A[m = spatial x][k = channel], scalar element builds
    short8 Ar = {0,0,0,0,0,0,0,0}, Ai = {0,0,0,0,0,0,0,0};
#pragma unroll
    for (int jj = 0; jj < 8; ++jj) {
      int ix = ((q*8 + jj)*6 + (w + ky))*18 + (m + kx);
      Ar[jj] = (short)sm[ix];
      Ai[jj] = (short)sm[3456 + ix];
    }
#pragma unroll
    for (int nt = 0; nt < 2; ++nt) {
      // B fragment: B[k = channel][n = out-channel], 16B-aligned contiguous loads
      const u16* pw = wb + ((((size_t)tap*2 + nt)*3)*16 + (size_t)m)*32 + q*8;
      short8 Wr  = *(const short8*)pw;
      short8 Wi  = *(const short8*)(pw + 512);
      short8 nWi = *(const short8*)(pw + 1024);
      accr[nt] = __builtin_amdgcn_mfma_f32_16x16x32_bf16(Ar, Wr,  accr[nt], 0, 0, 0);
      accr[nt] = __builtin_amdgcn_mfma_f32_16x16x32_bf16(Ai, nWi, accr[nt], 0, 0, 0);
      acci[nt] = __builtin_amdgcn_mfma_f32_16x16x32_bf16(Ar, Wi,  acci[nt], 0, 0, 0);
      acci[nt] = __builtin_amdgcn_mfma_f32_16x16x32_bf16(Ai, Wr,  acci[nt], 0, 0, 0);
    }
  }
  __syncthreads();   // done reading stage region; reuse sm for epilogue transpose

  // ---- epilogue: D layout col(lane&15)=out-ch, row(q*4+r)=pixel x-offset [m89] ----
  const int y = y0 + w;
#pragma unroll
  for (int nt = 0; nt < 2; ++nt) {
    int o = nt*16 + m;
    floatx4 cr = accr[nt], ci = acci[nt];
    size_t pbase = ((size_t)(b*32 + o)*HH + y)*WW;
#pragma unroll
    for (int r = 0; r < 4; ++r) {
      float pr = cr[r], pi = ci[r];
      int x = x0 + q*4 + r;
      if constexpr (MODE == 1) { pr = actf(pr); pi = actf(pi); }
      if constexpr (MODE == 2) {
        if (x < WW) {
          float dr = actdf(b2f(derb[pbase + x]));
          float di = actdf(b2f(derb[PE + pbase + x]));
          float nr = pr*dr - pi*di;
          pi = pr*di + pi*dr; pr = nr;
        }
      }
      sm[((o*2 + 0)*4 + w)*16 + q*4 + r] = f2b(pr);
      sm[((o*2 + 1)*4 + w)*16 + q*4 + r] = f2b(pi);
    }
  }
  __syncthreads();

  // ---- store: 256 jobs, one per thread, scalar u16 stores ----
  {
    int j = tid;
    int o = j >> 3; int ri = (j >> 2) & 1; int row = j & 3;
    const u16* p = &sm[((o*2 + ri)*4 + row)*16];
    size_t gb = (size_t)ri*PE + ((size_t)(b*32 + o)*HH + (y0 + row))*WW + x0;
    for (int pos = 0; pos < 16; ++pos) {
      int x = x0 + pos;
      if (x < WW) outb[gb + pos] = p[pos];
    }
  }
}

// ---------------- layer-1 forward: complex conv 1->32 + act, fp32 in -> bf16 planes ----
__global__ __launch_bounds__(256)
void l1fwd(const float* __restrict__ xp,   // R at 0, I at P1
           const float* __restrict__ wr, const float* __restrict__ wi,
           u16* __restrict__ outb)
{
  __shared__ float hR[10][34], hI[10][34];
  __shared__ float wt[9][32][2];
  const int tid = threadIdx.x;
  const int tx = tid & 31, ty = tid >> 5;
  const int x0 = blockIdx.x*32, y0 = blockIdx.y*8, b = blockIdx.z;

  // FIX (R4): 288 weight elements need a strided loop — `if (tid < 288)` with a
  // 256-thread block left wt[8][*] uninitialized (R2 NaN / R3 corruption source).
  for (int j = tid; j < 288; j += 256) {
    int o = j & 31, tap = j >> 5;
    wt[tap][o][0] = wr[o*9+tap]; wt[tap][o][1] = wi[o*9+tap];
  }
  for (int j = tid; j < 340; j += 256) {
    int yy = j / 34, xx = j - yy*34;
    int gy = y0 - 1 + yy, gx = x0 - 1 + xx;
    float vr = 0.f, vi = 0.f;
    if (gy >= 0 && gy < HH && gx >= 0 && gx < WW) {
      size_t o2 = (size_t)b*HWSZ + (size_t)gy*WW + gx;
      vr = xp[o2]; vi = xp[P1 + o2];
    }
    hR[yy][xx] = vr; hI[yy][xx] = vi;
  }
  __syncthreads();

  float accR[32], accI[32];
#pragma unroll
  for (int o = 0; o < 32; ++o) { accR[o] = 0.f; accI[o] = 0.f; }
#pragma unroll
  for (int tap = 0; tap < 9; ++tap) {
    int ky = tap/3, kx = tap - ky*3;
    float ar = hR[ty+ky][tx+kx], ai = hI[ty+ky][tx+kx];
#pragma unroll
    for (int o = 0; o < 32; ++o) {
      float wrv = wt[tap][o][0], wiv = wt[tap][o][1];
      accR[o] += ar*wrv - ai*wiv;
      accI[o] += ar*wiv + ai*wrv;
    }
  }
  int gx = x0 + tx, gy = y0 + ty;
  if (gx < WW) {
#pragma unroll
    for (int o = 0; o < 32; ++o) {
      size_t off = ((size_t)(b*32 + o)*HH + gy)*WW + gx;
      outb[off]      = f2b(actf(accR[o]));
      outb[PE + off] = f2b(actf(accI[o]));
    }
  }
}

// ---------------- layer-1 backward: complex convT 32->1, bf16 in -> fp32 planes ----
__global__ __launch_bounds__(256)
void l1bwd(const u16* __restrict__ gb,
           const float* __restrict__ wr, const float* __restrict__ wi,
           float* __restrict__ outp)    // R at 0, I at P1
{
  __shared__ u16 hR[8][10][34], hI[8][10][34];
  __shared__ float wt[32][9][2];
  const int tid = threadIdx.x;
  const int tx = tid & 31, ty = tid >> 5;
  const int x0 = blockIdx.x*32, y0 = blockIdx.y*8, b = blockIdx.z;

  // FIX (R4): same 288-element loop fix — channels 28..31 were uninitialized.
  for (int j = tid; j < 288; j += 256) {
    int c = j / 9, tap = j - c*9;
    wt[c][tap][0] = wr[c*9 + (8-tap)]; wt[c][tap][1] = wi[c*9 + (8-tap)];
  }

  float gr = 0.f, gi = 0.f;
  for (int c0 = 0; c0 < 32; c0 += 8) {
    __syncthreads();
    for (int j = tid; j < 2720; j += 256) {
      int cc = j / 340; int rem = j - cc*340;
      int yy = rem / 34, xx = rem - yy*34;
      int gy = y0 - 1 + yy, gx = x0 - 1 + xx;
      u16 vr = 0, vi = 0;
      if (gy >= 0 && gy < HH && gx >= 0 && gx < WW) {
        size_t o2 = ((size_t)(b*32 + c0 + cc)*HH + gy)*WW + gx;
        vr = gb[o2]; vi = gb[PE + o2];
      }
      hR[cc][yy][xx] = vr; hI[cc][yy][xx] = vi;
    }
    __syncthreads();
#pragma unroll 1
    for (int cc = 0; cc < 8; ++cc) {
#pragma unroll
      for (int tap = 0; tap < 9; ++tap) {
        int ky = tap/3, kx = tap - ky*3;
        float ar = b2f(hR[cc][ty+ky][tx+kx]);
        float ai = b2f(hI[cc][ty+ky][tx+kx]);
        float wrv = wt[c0+cc][tap][0], wiv = wt[c0+cc][tap][1];
        gr += ar*wrv - ai*wiv;
        gi += ar*wiv + ai*wrv;
      }
    }
  }
  int gx = x0 + tx, gy = y0 + ty;
  if (gx < WW) {
    size_t o2 = (size_t)b*HWSZ + (size_t)gy*WW + gx;
    outp[o2]      = gr;
    outp[P1 + o2] = gi;
  }
}

// ---------------- channel-norm normalize on bf16 planes ----------------
__global__ void normalize_b(u16* __restrict__ gb, const float* __restrict__ thr_p) {
  int i = blockIdx.x*256 + threadIdx.x;
  if (i >= (int)P1) return;
  int b = i / HWSZ, p = i - b*HWSZ;
  float thr = thr_p[0];
  size_t base = (size_t)b*32*HWSZ + p;
  float s = 0.f;
#pragma unroll
  for (int c = 0; c < 32; ++c) {
    float vr = b2f(gb[base + (size_t)c*HWSZ]);
    float vi = b2f(gb[PE + base + (size_t)c*HWSZ]);
    s += vr*vr + vi*vi;
  }
  float inv = 1.0f / fmaxf(sqrtf(s), thr);
#pragma unroll
  for (int c = 0; c < 32; ++c) {
    size_t a = base + (size_t)c*HWSZ;
    gb[a]      = f2b(b2f(gb[a]) * inv);
    gb[PE + a] = f2b(b2f(gb[PE + a]) * inv);
  }
}

// ---------------- DFT-by-matmul machinery (fp32) ----------------
__global__ void gen_dft(float2* __restrict__ M, int N, double sign, double scale) {
  int idx = blockIdx.x*256 + threadIdx.x;
  if (idx >= N*N) return;
  int r = idx / N, c = idx - r*N;
  long m = ((long)r * (long)c) % N;
  double a = sign * 2.0 * 3.14159265358979323846 * (double)m / (double)N;
  M[idx] = make_float2((float)(cos(a)*scale), (float)(sin(a)*scale));
}

__global__ void dft_row_planes(const float* __restrict__ xR, const float* __restrict__ xI,
                               float2* __restrict__ out, const float2* __restrict__ M) {
  int bh = blockIdx.x;
  int v = threadIdx.x; if (v >= WW) return;
  const float* rowR = xR + (size_t)bh*WW;
  const float* rowI = xI + (size_t)bh*WW;
  float ar = 0.f, ai = 0.f;
  for (int w = 0; w < WW; ++w) {
    float sr = rowR[w], si = rowI[w];
    float2 m = M[w*WW + v];
    ar += sr*m.x - si*m.y;
    ai += sr*m.y + si*m.x;
  }
  out[(size_t)bh*WW + v] = make_float2(ar, ai);
}

__global__ void dft_row_c(const float2* __restrict__ in, float2* __restrict__ out,
                          const float2* __restrict__ M) {
  int bh = blockIdx.x;
  int v = threadIdx.x; if (v >= WW) return;
  const float2* row = in + (size_t)bh*WW;
  float ar = 0.f, ai = 0.f;
  for (int w = 0; w < WW; ++w) {
    float2 s = row[w];
    float2 m = M[w*WW + v];
    ar += s.x*m.x - s.y*m.y;
    ai += s.x*m.y + s.y*m.x;
  }
  out[(size_t)bh*WW + v] = make_float2(ar, ai);
}

__global__ void dft_col_c(const float2* __restrict__ in, float2* __restrict__ out,
                          const float2* __restrict__ M) {
  int bu = blockIdx.x;
  int v = threadIdx.x; if (v >= WW) return;
  int b = bu / HH, u = bu - b*HH;
  const float2* base = in + (size_t)b*HWSZ;
  float ar = 0.f, ai = 0.f;
  for (int h = 0; h < HH; ++h) {
    float2 m = M[u*HH + h];
    float2 s = base[(size_t)h*WW + v];
    ar += s.x*m.x - s.y*m.y;
    ai += s.x*m.y + s.y*m.x;
  }
  out[(size_t)bu*WW + v] = make_float2(ar, ai);
}

// ---------------- small pointwise kernels (fp32) ----------------
__global__ void mask2_kernel(float2* __restrict__ t, const float* __restrict__ mask) {
  int i = blockIdx.x*256 + threadIdx.x;
  if (i >= (int)P1) return;
  float m = mask[i % HWSZ]; float mm = m*m;
  float2 v = t[i];
  t[i] = make_float2(v.x*mm, v.y*mm);
}

__global__ void maskk_kernel(const float* __restrict__ k, const float* __restrict__ mask,
                             float2* __restrict__ t) {
  int i = blockIdx.x*256 + threadIdx.x;
  if (i >= (int)P1) return;
  int b = i / HWSZ, p = i - b*HWSZ;
  float m = mask[p];
  t[i] = make_float2(m * k[(size_t)b*2*HWSZ + p], m * k[(size_t)b*2*HWSZ + HWSZ + p]);
}

__global__ void unpack_kernel(const float* __restrict__ x, float* __restrict__ xr,
                              float* __restrict__ xi) {
  int i = blockIdx.x*256 + threadIdx.x;
  if (i >= (int)P1) return;
  int b = i / HWSZ, p = i - b*HWSZ;
  xr[i] = x[(size_t)b*2*HWSZ + p];
  xi[i] = x[(size_t)b*2*HWSZ + HWSZ + p];
}

__global__ void update_kernel(float* __restrict__ xr, float* __restrict__ xi,
                              const float2* __restrict__ gradf, const float2* __restrict__ cterm,
                              const float* __restrict__ grR, const float* __restrict__ grI,
                              const float* __restrict__ alphas, const float* __restrict__ betas,
                              int phase) {
  int i = blockIdx.x*256 + threadIdx.x;
  if (i >= (int)P1) return;
  float a = alphas[phase], bb = betas[phase];
  float gfr = gradf[i].x - cterm[i].x;
  float gfi = gradf[i].y - cterm[i].y;
  xr[i] -= a*gfr + bb*grR[i];
  xi[i] -= a*gfi + bb*grI[i];
}

__global__ void pack_kernel(const float* __restrict__ x1r, const float* __restrict__ x1i,
                            const float* __restrict__ x2r, const float* __restrict__ x2i,
                            float* __restrict__ out) {
  int i = blockIdx.x*256 + threadIdx.x;
  if (i >= (int)P1) return;
  int b = i / HWSZ, p = i - b*HWSZ;
  size_t ob = (size_t)b*4*HWSZ;
  out[ob + p]          = x1r[i];
  out[ob + HWSZ + p]   = x1i[i];
  out[ob + 2*HWSZ + p] = x2r[i];
  out[ob + 3*HWSZ + p] = x2i[i];
}

// ---------------- launch ----------------
extern "C" void kernel_launch(void* const* d_in, const int* in_sizes, int n_in,
                              void* d_out, int out_size, void* d_ws, size_t ws_size,
                              hipStream_t stream) {
  (void)in_sizes; (void)n_in; (void)out_size; (void)ws_size;
  const float* x1in = (const float*)d_in[0];
  const float* x2in = (const float*)d_in[1];
  const float* k1   = (const float*)d_in[2];
  const float* k2   = (const float*)d_in[3];
  const float* mask = (const float*)d_in[4];
  const float* cw[16];
  for (int i = 0; i < 16; ++i) cw[i] = (const float*)d_in[5+i];
  const float* thr1 = (const float*)d_in[21];
  const float* thr2 = (const float*)d_in[22];
  const float* al1  = (const float*)d_in[23];
  const float* al2  = (const float*)d_in[24];
  const float* be1  = (const float*)d_in[25];
  const float* be2  = (const float*)d_in[26];
  float* out = (float*)d_out;

  // ---- workspace layout: bf16 region first, then fp32 region ----
  u16* U = (u16*)d_ws;
  size_t uoff = 0;
  auto alloc_u = [&](size_t n){ u16* p = U + uoff; uoff += (n + 15) & ~(size_t)15; return p; };
  u16* act1 = alloc_u(2*PE);
  u16* act2 = alloc_u(2*PE);
  u16* act3 = alloc_u(2*PE);
  u16* w4b  = alloc_u(2*PE);
  u16* gA   = alloc_u(2*PE);
  u16* wp[12];
  for (int i = 0; i < 12; ++i) wp[i] = alloc_u(27648);

  float* F = (float*)(U + uoff);
  size_t off = 0;
  auto alloc_f = [&](size_t n){ float* p = F + off; off += (n + 3) & ~(size_t)3; return p; };
  float* x1p = alloc_f(2*P1);
  float* x2p = alloc_f(2*P1);
  float* grp = alloc_f(2*P1);
  float2* t1  = (float2*)alloc_f(2*P1);
  float2* t2  = (float2*)alloc_f(2*P1);
  float2* gf  = (float2*)alloc_f(2*P1);
  float2* ct1 = (float2*)alloc_f(2*P1);
  float2* ct2 = (float2*)alloc_f(2*P1);
  float2* EWf = (float2*)alloc_f(2*(size_t)WW*WW);
  float2* EWi = (float2*)alloc_f(2*(size_t)WW*WW);
  float2* EHf = (float2*)alloc_f(2*(size_t)HH*HH);
  float2* EHi = (float2*)alloc_f(2*(size_t)HH*HH);

  const dim3 MG(12, 40, BB);      // mfma conv grid: 16x4 tiles
  const dim3 DG(6, 20, BB);       // direct conv grid: 32x8 tiles
  const int NP1 = (int)((P1 + 255)/256);
  const int DFTG = BB*HH;
  const int DFTB = 192;

  // twiddles
  gen_dft<<<(WW*WW+255)/256, 256, 0, stream>>>(EWf, WW, -1.0, 1.0);
  gen_dft<<<(WW*WW+255)/256, 256, 0, stream>>>(EWi, WW,  1.0, 1.0/(double)WW);
  gen_dft<<<(HH*HH+255)/256, 256, 0, stream>>>(EHf, HH, -1.0, 1.0);
  gen_dft<<<(HH*HH+255)/256, 256, 0, stream>>>(EHi, HH,  1.0, 1.0/(double)HH);

  // weight prep: branch A fwd L2,L3,L4 / bwd L4,L3,L2 ; branch B same (+6)
  prep_w3<<<36, 256, 0, stream>>>(cw[2],  cw[3],  wp[0], 0);
  prep_w3<<<36, 256, 0, stream>>>(cw[4],  cw[5],  wp[1], 0);
  prep_w3<<<36, 256, 0, stream>>>(cw[6],  cw[7],  wp[2], 0);
  prep_w3<<<36, 256, 0, stream>>>(cw[6],  cw[7],  wp[3], 1);
  prep_w3<<<36, 256, 0, stream>>>(cw[4],  cw[5],  wp[4], 1);
  prep_w3<<<36, 256, 0, stream>>>(cw[2],  cw[3],  wp[5], 1);
  prep_w3<<<36, 256, 0, stream>>>(cw[10], cw[11], wp[6], 0);
  prep_w3<<<36, 256, 0, stream>>>(cw[12], cw[13], wp[7], 0);
  prep_w3<<<36, 256, 0, stream>>>(cw[14], cw[15], wp[8], 0);
  prep_w3<<<36, 256, 0, stream>>>(cw[14], cw[15], wp[9], 1);
  prep_w3<<<36, 256, 0, stream>>>(cw[12], cw[13], wp[10], 1);
  prep_w3<<<36, 256, 0, stream>>>(cw[10], cw[11], wp[11], 1);

  // unpack x into fp32 planes
  unpack_kernel<<<NP1, 256, 0, stream>>>(x1in, x1p, x1p + P1);
  unpack_kernel<<<NP1, 256, 0, stream>>>(x2in, x2p, x2p + P1);

  // cterm = ifft2(mask * k) (phase-invariant)
  maskk_kernel<<<NP1, 256, 0, stream>>>(k1, mask, t1);
  dft_col_c<<<DFTG, DFTB, 0, stream>>>(t1, t2, EHi);
  dft_row_c<<<DFTG, DFTB, 0, stream>>>(t2, ct1, EWi);
  maskk_kernel<<<NP1, 256, 0, stream>>>(k2, mask, t1);
  dft_col_c<<<DFTG, DFTB, 0, stream>>>(t1, t2, EHi);
  dft_row_c<<<DFTG, DFTB, 0, stream>>>(t2, ct2, EWi);

  auto run_gradr = [&](float* xp, const float* c1r, const float* c1i,
                       u16* const* W, const float* thrp) {
    l1fwd<<<DG, 256, 0, stream>>>(xp, c1r, c1i, act1);
    conv_mfma<1><<<MG, 256, 0, stream>>>(act1, W[0], act2, nullptr);
    conv_mfma<1><<<MG, 256, 0, stream>>>(act2, W[1], act3, nullptr);
    conv_mfma<0><<<MG, 256, 0, stream>>>(act3, W[2], w4b, nullptr);
    normalize_b<<<NP1, 256, 0, stream>>>(w4b, thrp);
    conv_mfma<2><<<MG, 256, 0, stream>>>(w4b, W[3], gA,   act3);
    conv_mfma<2><<<MG, 256, 0, stream>>>(gA,  W[4], act3, act2);
    conv_mfma<2><<<MG, 256, 0, stream>>>(act3, W[5], act2, act1);
    l1bwd<<<DG, 256, 0, stream>>>(act2, c1r, c1i, grp);
  };

  auto run_gradf = [&](float* xp) {
    dft_row_planes<<<DFTG, DFTB, 0, stream>>>(xp, xp + P1, t1, EWf);
    dft_col_c<<<DFTG, DFTB, 0, stream>>>(t1, t2, EHf);
    mask2_kernel<<<NP1, 256, 0, stream>>>(t2, mask);
    dft_col_c<<<DFTG, DFTB, 0, stream>>>(t2, t1, EHi);
    dft_row_c<<<DFTG, DFTB, 0, stream>>>(t1, gf, EWi);
  };

  u16* WA[6] = {wp[0], wp[1], wp[2], wp[3], wp[4], wp[5]};
  u16* WB[6] = {wp[6], wp[7], wp[8], wp[9], wp[10], wp[11]};

  for (int ph = 0; ph < 3; ++ph) {
    run_gradr(x1p, cw[0], cw[1], WA, thr1);
    run_gradf(x1p);
    update_kernel<<<NP1, 256, 0, stream>>>(x1p, x1p+P1, gf, ct1, grp, grp+P1, al1, be1, ph);
    run_gradr(x2p, cw[8], cw[9], WB, thr2);
    run_gradf(x2p);
    update_kernel<<<NP1, 256, 0, stream>>>(x2p, x2p+P1, gf, ct2, grp, grp+P1, al2, be2, ph);
  }

  pack_kernel<<<NP1, 256, 0, stream>>>(x1p, x1p+P1, x2p, x2p+P1, out);
}

// Round 5
// 5144.509 us; speedup vs baseline: 11.5785x; 1.9316x over previous
//
#include <hip/hip_runtime.h>
#include <math.h>

#define HH 160
#define WW 180
#define HWSZ (HH*WW)
#define BB 8
#define P1 ((size_t)BB*HWSZ)            // 230400
#define PE ((size_t)BB*32*HWSZ)         // 7372800 (one 32-ch plane set)

typedef unsigned short u16;
typedef unsigned long long ull;
typedef __attribute__((ext_vector_type(8))) short short8;
typedef __attribute__((ext_vector_type(2))) unsigned long long ull2;
typedef __attribute__((ext_vector_type(4))) float floatx4;

// ---------------- bf16 helpers ----------------
__device__ __forceinline__ u16 f2b(float f) {
  unsigned u = __builtin_bit_cast(unsigned, f);
  unsigned r = (u + 0x7fffu + ((u >> 16) & 1u)) >> 16;
  return (u16)r;
}
__device__ __forceinline__ float b2f(u16 h) {
  return __builtin_bit_cast(float, ((unsigned)h) << 16);
}

// ---------------- activation (eq. 33), delta = 0.01 ----------------
__device__ __forceinline__ float actf(float x) {
  float q = x*x*25.0f + 0.5f*x + 0.0025f;
  float r = fmaxf(x, 0.0f);
  return (fabsf(x) > 0.01f) ? r : q;
}
__device__ __forceinline__ float actdf(float x) {
  float q = x*50.0f + 0.5f;
  float r = (x > 0.0f) ? 1.0f : 0.0f;
  return (fabsf(x) > 0.01f) ? r : q;
}

// ---------------- weight prep: fp32 [o][c][9] -> bf16 [tap][nt][plane(r,i,-i)][o16][c32]
__global__ void prep_w3(const float* __restrict__ wr, const float* __restrict__ wi,
                        u16* __restrict__ dst, int bwd) {
  int idx = blockIdx.x*256 + threadIdx.x;
  if (idx >= 9*32*32) return;
  int tap = idx >> 10; int rem = idx & 1023; int o = rem >> 5; int c = rem & 31;
  int s = bwd ? ((c*32 + o)*9 + (8 - tap)) : ((o*32 + c)*9 + tap);
  float vr = wr[s], vi = wi[s];
  int nt = o >> 4, m = o & 15;
  size_t base = ((((size_t)tap*2 + nt)*3)*16 + (size_t)m)*32 + c;
  dst[base]        = f2b(vr);
  dst[base + 512]  = f2b(vi);
  dst[base + 1024] = f2b(-vi);
}

// ---------------- MFMA complex conv 32->32, 3x3 SAME, implicit GEMM -----------------
// Tile: 62 wide x 4 high. 4 waves, wave w -> output row y0+w, 4 m-segments of 16 px.
// LDS stage: u16 [plane2][row6][col66][ch36pad]  (wave-per-row coalesced fill)
// Epilogue: fp32 acc -> LDS [row4][px64][och33pad] float2 -> coalesced px-major pass.
// MODE: 0 plain, 1 act, 2 complex-multiply by actdf(der planes)
template<int MODE>
__global__ __launch_bounds__(256)
void conv_mfma(const u16* __restrict__ inb, const u16* __restrict__ wb,
               u16* __restrict__ outb, const u16* __restrict__ derb)
{
  __shared__ alignas(16) char smraw[67584];
  u16*    stg = (u16*)smraw;      // [2][6][66][36]  (57 KB)
  float2* epi = (float2*)smraw;   // [4][64][33]     (67.5 KB, aliased after sync)

  const int tid = threadIdx.x;
  const int lane = tid & 63, wv = tid >> 6;
  const int x0 = blockIdx.x * 62, y0 = blockIdx.y * 4, b = blockIdx.z;

  // zero the 2 pad cols (64,65) read only by discarded edge pixels
  for (int j = tid; j < 864; j += 256) {
    int ch = j % 36; int r2 = j / 36;        // r2 in [0,24)
    int cbit = r2 & 1; int prow = r2 >> 1;   // prow = plane*6+row
    stg[(prow*66 + 64 + cbit)*36 + ch] = 0;
  }

  // ---- stage: one wave per (plane,ch,row); 64 lanes = 64 contiguous cols ----
  for (int j = wv; j < 384; j += 4) {
    int plane = j / 192; int rem = j - plane*192;
    int ch = rem / 6; int row = rem - ch*6;
    int gy = y0 - 1 + row;
    int gx = x0 - 1 + lane;
    u16 v = 0;
    if (gy >= 0 && gy < HH && gx >= 0 && gx < WW)
      v = inb[(size_t)plane*PE + ((size_t)(b*32+ch)*HH + gy)*WW + gx];
    stg[((plane*6 + row)*66 + lane)*36 + ch] = v;
  }
  __syncthreads();

  const int m = lane & 15, q = lane >> 4;

  floatx4 accr[4][2], acci[4][2];   // [seg][nt]
#pragma unroll
  for (int s = 0; s < 4; ++s)
#pragma unroll
    for (int nt = 0; nt < 2; ++nt) {
      accr[s][nt] = (floatx4){0.f,0.f,0.f,0.f};
      acci[s][nt] = (floatx4){0.f,0.f,0.f,0.f};
    }

#pragma unroll
  for (int tap = 0; tap < 9; ++tap) {
    const int ky = tap / 3, kx = tap - ky*3;
    short8 Ar[4], Ai[4];
#pragma unroll
    for (int s = 0; s < 4; ++s) {
      int cu = (((wv + ky))*66 + (s*16 + m + kx))*36 + q*8;   // 8B-aligned
      const ull* pR = (const ull*)&stg[cu];
      const ull* pI = (const ull*)&stg[cu + 6*66*36];
      ull2 vr; vr.x = pR[0]; vr.y = pR[1];
      ull2 vi; vi.x = pI[0]; vi.y = pI[1];
      Ar[s] = __builtin_bit_cast(short8, vr);
      Ai[s] = __builtin_bit_cast(short8, vi);
    }
#pragma unroll
    for (int nt = 0; nt < 2; ++nt) {
      const u16* pw = wb + ((size_t)(tap*2 + nt)*3)*512 + (size_t)m*32 + q*8;
      short8 Wr  = *(const short8*)pw;
      short8 Wi  = *(const short8*)(pw + 512);
      short8 nWi = *(const short8*)(pw + 1024);
#pragma unroll
      for (int s = 0; s < 4; ++s) {
        accr[s][nt] = __builtin_amdgcn_mfma_f32_16x16x32_bf16(Ar[s], Wr,  accr[s][nt], 0, 0, 0);
        accr[s][nt] = __builtin_amdgcn_mfma_f32_16x16x32_bf16(Ai[s], nWi, accr[s][nt], 0, 0, 0);
        acci[s][nt] = __builtin_amdgcn_mfma_f32_16x16x32_bf16(Ar[s], Wi,  acci[s][nt], 0, 0, 0);
        acci[s][nt] = __builtin_amdgcn_mfma_f32_16x16x32_bf16(Ai[s], Wr,  acci[s][nt], 0, 0, 0);
      }
    }
  }
  __syncthreads();   // all stage reads done; alias LDS as epi buffer

  // ---- epilogue spill: D layout col(lane&15)=och_lo, row(q*4+r)=px offset [R4-verified]
#pragma unroll
  for (int s = 0; s < 4; ++s)
#pragma unroll
    for (int nt = 0; nt < 2; ++nt)
#pragma unroll
      for (int r = 0; r < 4; ++r) {
        int px = s*16 + q*4 + r;
        int och = nt*16 + m;
        epi[((size_t)wv*64 + px)*33 + och] = make_float2(accr[s][nt][r], acci[s][nt][r]);
      }
  __syncthreads();

  // ---- output pass: 128 (och,row) jobs over 4 waves; lane = pixel (coalesced) ----
  for (int j = wv; j < 128; j += 4) {
    int och = j >> 2, row = j & 3;
    int p = lane;
    int x = x0 + p;
    int y = y0 + row;
    if (p < 62 && x < WW) {
      float2 v = epi[((size_t)row*64 + p)*33 + och];
      float pr = v.x, pi = v.y;
      size_t gb = ((size_t)(b*32 + och)*HH + y)*WW + x;
      if constexpr (MODE == 1) { pr = actf(pr); pi = actf(pi); }
      if constexpr (MODE == 2) {
        float dr = actdf(b2f(derb[gb]));
        float di = actdf(b2f(derb[PE + gb]));
        float nr = pr*dr - pi*di;
        pi = pr*di + pi*dr; pr = nr;
      }
      outb[gb]      = f2b(pr);
      outb[PE + gb] = f2b(pi);
    }
  }
}

// ---------------- layer-1 forward: complex conv 1->32 + act, fp32 in -> bf16 planes ----
__global__ __launch_bounds__(256)
void l1fwd(const float* __restrict__ xp,   // R at 0, I at P1
           const float* __restrict__ wr, const float* __restrict__ wi,
           u16* __restrict__ outb)
{
  __shared__ float hR[10][34], hI[10][34];
  __shared__ float wt[9][32][2];
  const int tid = threadIdx.x;
  const int tx = tid & 31, ty = tid >> 5;
  const int x0 = blockIdx.x*32, y0 = blockIdx.y*8, b = blockIdx.z;

  for (int j = tid; j < 288; j += 256) {
    int o = j & 31, tap = j >> 5;
    wt[tap][o][0] = wr[o*9+tap]; wt[tap][o][1] = wi[o*9+tap];
  }
  for (int j = tid; j < 340; j += 256) {
    int yy = j / 34, xx = j - yy*34;
    int gy = y0 - 1 + yy, gx = x0 - 1 + xx;
    float vr = 0.f, vi = 0.f;
    if (gy >= 0 && gy < HH && gx >= 0 && gx < WW) {
      size_t o2 = (size_t)b*HWSZ + (size_t)gy*WW + gx;
      vr = xp[o2]; vi = xp[P1 + o2];
    }
    hR[yy][xx] = vr; hI[yy][xx] = vi;
  }
  __syncthreads();

  float accR[32], accI[32];
#pragma unroll
  for (int o = 0; o < 32; ++o) { accR[o] = 0.f; accI[o] = 0.f; }
#pragma unroll
  for (int tap = 0; tap < 9; ++tap) {
    int ky = tap/3, kx = tap - ky*3;
    float ar = hR[ty+ky][tx+kx], ai = hI[ty+ky][tx+kx];
#pragma unroll
    for (int o = 0; o < 32; ++o) {
      float wrv = wt[tap][o][0], wiv = wt[tap][o][1];
      accR[o] += ar*wrv - ai*wiv;
      accI[o] += ar*wiv + ai*wrv;
    }
  }
  int gx = x0 + tx, gy = y0 + ty;
  if (gx < WW) {
#pragma unroll
    for (int o = 0; o < 32; ++o) {
      size_t off = ((size_t)(b*32 + o)*HH + gy)*WW + gx;
      outb[off]      = f2b(actf(accR[o]));
      outb[PE + off] = f2b(actf(accI[o]));
    }
  }
}

// ---------------- layer-1 backward: complex convT 32->1, bf16 in -> fp32 planes ----
__global__ __launch_bounds__(256)
void l1bwd(const u16* __restrict__ gb,
           const float* __restrict__ wr, const float* __restrict__ wi,
           float* __restrict__ outp)    // R at 0, I at P1
{
  __shared__ u16 hR[8][10][34], hI[8][10][34];
  __shared__ float wt[32][9][2];
  const int tid = threadIdx.x;
  const int tx = tid & 31, ty = tid >> 5;
  const int x0 = blockIdx.x*32, y0 = blockIdx.y*8, b = blockIdx.z;

  for (int j = tid; j < 288; j += 256) {
    int c = j / 9, tap = j - c*9;
    wt[c][tap][0] = wr[c*9 + (8-tap)]; wt[c][tap][1] = wi[c*9 + (8-tap)];
  }

  float gr = 0.f, gi = 0.f;
  for (int c0 = 0; c0 < 32; c0 += 8) {
    __syncthreads();
    for (int j = tid; j < 2720; j += 256) {
      int cc = j / 340; int rem = j - cc*340;
      int yy = rem / 34, xx = rem - yy*34;
      int gy = y0 - 1 + yy, gx = x0 - 1 + xx;
      u16 vr = 0, vi = 0;
      if (gy >= 0 && gy < HH && gx >= 0 && gx < WW) {
        size_t o2 = ((size_t)(b*32 + c0 + cc)*HH + gy)*WW + gx;
        vr = gb[o2]; vi = gb[PE + o2];
      }
      hR[cc][yy][xx] = vr; hI[cc][yy][xx] = vi;
    }
    __syncthreads();
#pragma unroll 1
    for (int cc = 0; cc < 8; ++cc) {
#pragma unroll
      for (int tap = 0; tap < 9; ++tap) {
        int ky = tap/3, kx = tap - ky*3;
        float ar = b2f(hR[cc][ty+ky][tx+kx]);
        float ai = b2f(hI[cc][ty+ky][tx+kx]);
        float wrv = wt[c0+cc][tap][0], wiv = wt[c0+cc][tap][1];
        gr += ar*wrv - ai*wiv;
        gi += ar*wiv + ai*wrv;
      }
    }
  }
  int gx = x0 + tx, gy = y0 + ty;
  if (gx < WW) {
    size_t o2 = (size_t)b*HWSZ + (size_t)gy*WW + gx;
    outp[o2]      = gr;
    outp[P1 + o2] = gi;
  }
}

// ---------------- channel-norm normalize on bf16 planes ----------------
__global__ void normalize_b(u16* __restrict__ gb, const float* __restrict__ thr_p) {
  int i = blockIdx.x*256 + threadIdx.x;
  if (i >= (int)P1) return;
  int b = i / HWSZ, p = i - b*HWSZ;
  float thr = thr_p[0];
  size_t base = (size_t)b*32*HWSZ + p;
  float s = 0.f;
#pragma unroll
  for (int c = 0; c < 32; ++c) {
    float vr = b2f(gb[base + (size_t)c*HWSZ]);
    float vi = b2f(gb[PE + base + (size_t)c*HWSZ]);
    s += vr*vr + vi*vi;
  }
  float inv = 1.0f / fmaxf(sqrtf(s), thr);
#pragma unroll
  for (int c = 0; c < 32; ++c) {
    size_t a = base + (size_t)c*HWSZ;
    gb[a]      = f2b(b2f(gb[a]) * inv);
    gb[PE + a] = f2b(b2f(gb[PE + a]) * inv);
  }
}

// ---------------- DFT-by-matmul machinery (fp32) ----------------
__global__ void gen_dft(float2* __restrict__ M, int N, double sign, double scale) {
  int idx = blockIdx.x*256 + threadIdx.x;
  if (idx >= N*N) return;
  int r = idx / N, c = idx - r*N;
  long m = ((long)r * (long)c) % N;
  double a = sign * 2.0 * 3.14159265358979323846 * (double)m / (double)N;
  M[idx] = make_float2((float)(cos(a)*scale), (float)(sin(a)*scale));
}

__global__ void dft_row_planes(const float* __restrict__ xR, const float* __restrict__ xI,
                               float2* __restrict__ out, const float2* __restrict__ M) {
  int bh = blockIdx.x;
  int v = threadIdx.x; if (v >= WW) return;
  const float* rowR = xR + (size_t)bh*WW;
  const float* rowI = xI + (size_t)bh*WW;
  float ar = 0.f, ai = 0.f;
  for (int w = 0; w < WW; ++w) {
    float sr = rowR[w], si = rowI[w];
    float2 m = M[w*WW + v];
    ar += sr*m.x - si*m.y;
    ai += sr*m.y + si*m.x;
  }
  out[(size_t)bh*WW + v] = make_float2(ar, ai);
}

__global__ void dft_row_c(const float2* __restrict__ in, float2* __restrict__ out,
                          const float2* __restrict__ M) {
  int bh = blockIdx.x;
  int v = threadIdx.x; if (v >= WW) return;
  const float2* row = in + (size_t)bh*WW;
  float ar = 0.f, ai = 0.f;
  for (int w = 0; w < WW; ++w) {
    float2 s = row[w];
    float2 m = M[w*WW + v];
    ar += s.x*m.x - s.y*m.y;
    ai += s.x*m.y + s.y*m.x;
  }
  out[(size_t)bh*WW + v] = make_float2(ar, ai);
}

__global__ void dft_col_c(const float2* __restrict__ in, float2* __restrict__ out,
                          const float2* __restrict__ M) {
  int bu = blockIdx.x;
  int v = threadIdx.x; if (v >= WW) return;
  int b = bu / HH, u = bu - b*HH;
  const float2* base = in + (size_t)b*HWSZ;
  float ar = 0.f, ai = 0.f;
  for (int h = 0; h < HH; ++h) {
    float2 m = M[u*HH + h];
    float2 s = base[(size_t)h*WW + v];
    ar += s.x*m.x - s.y*m.y;
    ai += s.x*m.y + s.y*m.x;
  }
  out[(size_t)bu*WW + v] = make_float2(ar, ai);
}

// ---------------- small pointwise kernels (fp32) ----------------
__global__ void mask2_kernel(float2* __restrict__ t, const float* __restrict__ mask) {
  int i = blockIdx.x*256 + threadIdx.x;
  if (i >= (int)P1) return;
  float m = mask[i % HWSZ]; float mm = m*m;
  float2 v = t[i];
  t[i] = make_float2(v.x*mm, v.y*mm);
}

__global__ void maskk_kernel(const float* __restrict__ k, const float* __restrict__ mask,
                             float2* __restrict__ t) {
  int i = blockIdx.x*256 + threadIdx.x;
  if (i >= (int)P1) return;
  int b = i / HWSZ, p = i - b*HWSZ;
  float m = mask[p];
  t[i] = make_float2(m * k[(size_t)b*2*HWSZ + p], m * k[(size_t)b*2*HWSZ + HWSZ + p]);
}

__global__ void unpack_kernel(const float* __restrict__ x, float* __restrict__ xr,
                              float* __restrict__ xi) {
  int i = blockIdx.x*256 + threadIdx.x;
  if (i >= (int)P1) return;
  int b = i / HWSZ, p = i - b*HWSZ;
  xr[i] = x[(size_t)b*2*HWSZ + p];
  xi[i] = x[(size_t)b*2*HWSZ + HWSZ + p];
}

__global__ void update_kernel(float* __restrict__ xr, float* __restrict__ xi,
                              const float2* __restrict__ gradf, const float2* __restrict__ cterm,
                              const float* __restrict__ grR, const float* __restrict__ grI,
                              const float* __restrict__ alphas, const float* __restrict__ betas,
                              int phase) {
  int i = blockIdx.x*256 + threadIdx.x;
  if (i >= (int)P1) return;
  float a = alphas[phase], bb = betas[phase];
  float gfr = gradf[i].x - cterm[i].x;
  float gfi = gradf[i].y - cterm[i].y;
  xr[i] -= a*gfr + bb*grR[i];
  xi[i] -= a*gfi + bb*grI[i];
}

__global__ void pack_kernel(const float* __restrict__ x1r, const float* __restrict__ x1i,
                            const float* __restrict__ x2r, const float* __restrict__ x2i,
                            float* __restrict__ out) {
  int i = blockIdx.x*256 + threadIdx.x;
  if (i >= (int)P1) return;
  int b = i / HWSZ, p = i - b*HWSZ;
  size_t ob = (size_t)b*4*HWSZ;
  out[ob + p]          = x1r[i];
  out[ob + HWSZ + p]   = x1i[i];
  out[ob + 2*HWSZ + p] = x2r[i];
  out[ob + 3*HWSZ + p] = x2i[i];
}

// ---------------- launch ----------------
extern "C" void kernel_launch(void* const* d_in, const int* in_sizes, int n_in,
                              void* d_out, int out_size, void* d_ws, size_t ws_size,
                              hipStream_t stream) {
  (void)in_sizes; (void)n_in; (void)out_size; (void)ws_size;
  const float* x1in = (const float*)d_in[0];
  const float* x2in = (const float*)d_in[1];
  const float* k1   = (const float*)d_in[2];
  const float* k2   = (const float*)d_in[3];
  const float* mask = (const float*)d_in[4];
  const float* cw[16];
  for (int i = 0; i < 16; ++i) cw[i] = (const float*)d_in[5+i];
  const float* thr1 = (const float*)d_in[21];
  const float* thr2 = (const float*)d_in[22];
  const float* al1  = (const float*)d_in[23];
  const float* al2  = (const float*)d_in[24];
  const float* be1  = (const float*)d_in[25];
  const float* be2  = (const float*)d_in[26];
  float* out = (float*)d_out;

  // ---- workspace layout: bf16 region first, then fp32 region ----
  u16* U = (u16*)d_ws;
  size_t uoff = 0;
  auto alloc_u = [&](size_t n){ u16* p = U + uoff; uoff += (n + 15) & ~(size_t)15; return p; };
  u16* act1 = alloc_u(2*PE);
  u16* act2 = alloc_u(2*PE);
  u16* act3 = alloc_u(2*PE);
  u16* w4b  = alloc_u(2*PE);
  u16* gA   = alloc_u(2*PE);
  u16* wp[12];
  for (int i = 0; i < 12; ++i) wp[i] = alloc_u(27648);

  float* F = (float*)(U + uoff);
  size_t off = 0;
  auto alloc_f = [&](size_t n){ float* p = F + off; off += (n + 3) & ~(size_t)3; return p; };
  float* x1p = alloc_f(2*P1);
  float* x2p = alloc_f(2*P1);
  float* grp = alloc_f(2*P1);
  float2* t1  = (float2*)alloc_f(2*P1);
  float2* t2  = (float2*)alloc_f(2*P1);
  float2* gf  = (float2*)alloc_f(2*P1);
  float2* ct1 = (float2*)alloc_f(2*P1);
  float2* ct2 = (float2*)alloc_f(2*P1);
  float2* EWf = (float2*)alloc_f(2*(size_t)WW*WW);
  float2* EWi = (float2*)alloc_f(2*(size_t)WW*WW);
  float2* EHf = (float2*)alloc_f(2*(size_t)HH*HH);
  float2* EHi = (float2*)alloc_f(2*(size_t)HH*HH);

  const dim3 MG(3, 40, BB);       // mfma conv grid: 62x4 tiles
  const dim3 DG(6, 20, BB);       // direct conv grid: 32x8 tiles
  const int NP1 = (int)((P1 + 255)/256);
  const int DFTG = BB*HH;
  const int DFTB = 192;

  // twiddles
  gen_dft<<<(WW*WW+255)/256, 256, 0, stream>>>(EWf, WW, -1.0, 1.0);
  gen_dft<<<(WW*WW+255)/256, 256, 0, stream>>>(EWi, WW,  1.0, 1.0/(double)WW);
  gen_dft<<<(HH*HH+255)/256, 256, 0, stream>>>(EHf, HH, -1.0, 1.0);
  gen_dft<<<(HH*HH+255)/256, 256, 0, stream>>>(EHi, HH,  1.0, 1.0/(double)HH);

  // weight prep: branch A fwd L2,L3,L4 / bwd L4,L3,L2 ; branch B same (+6)
  prep_w3<<<36, 256, 0, stream>>>(cw[2],  cw[3],  wp[0], 0);
  prep_w3<<<36, 256, 0, stream>>>(cw[4],  cw[5],  wp[1], 0);
  prep_w3<<<36, 256, 0, stream>>>(cw[6],  cw[7],  wp[2], 0);
  prep_w3<<<36, 256, 0, stream>>>(cw[6],  cw[7],  wp[3], 1);
  prep_w3<<<36, 256, 0, stream>>>(cw[4],  cw[5],  wp[4], 1);
  prep_w3<<<36, 256, 0, stream>>>(cw[2],  cw[3],  wp[5], 1);
  prep_w3<<<36, 256, 0, stream>>>(cw[10], cw[11], wp[6], 0);
  prep_w3<<<36, 256, 0, stream>>>(cw[12], cw[13], wp[7], 0);
  prep_w3<<<36, 256, 0, stream>>>(cw[14], cw[15], wp[8], 0);
  prep_w3<<<36, 256, 0, stream>>>(cw[14], cw[15], wp[9], 1);
  prep_w3<<<36, 256, 0, stream>>>(cw[12], cw[13], wp[10], 1);
  prep_w3<<<36, 256, 0, stream>>>(cw[10], cw[11], wp[11], 1);

  // unpack x into fp32 planes
  unpack_kernel<<<NP1, 256, 0, stream>>>(x1in, x1p, x1p + P1);
  unpack_kernel<<<NP1, 256, 0, stream>>>(x2in, x2p, x2p + P1);

  // cterm = ifft2(mask * k) (phase-invariant)
  maskk_kernel<<<NP1, 256, 0, stream>>>(k1, mask, t1);
  dft_col_c<<<DFTG, DFTB, 0, stream>>>(t1, t2, EHi);
  dft_row_c<<<DFTG, DFTB, 0, stream>>>(t2, ct1, EWi);
  maskk_kernel<<<NP1, 256, 0, stream>>>(k2, mask, t1);
  dft_col_c<<<DFTG, DFTB, 0, stream>>>(t1, t2, EHi);
  dft_row_c<<<DFTG, DFTB, 0, stream>>>(t2, ct2, EWi);

  auto run_gradr = [&](float* xp, const float* c1r, const float* c1i,
                       u16* const* W, const float* thrp) {
    l1fwd<<<DG, 256, 0, stream>>>(xp, c1r, c1i, act1);
    conv_mfma<1><<<MG, 256, 0, stream>>>(act1, W[0], act2, nullptr);
    conv_mfma<1><<<MG, 256, 0, stream>>>(act2, W[1], act3, nullptr);
    conv_mfma<0><<<MG, 256, 0, stream>>>(act3, W[2], w4b, nullptr);
    normalize_b<<<NP1, 256, 0, stream>>>(w4b, thrp);
    conv_mfma<2><<<MG, 256, 0, stream>>>(w4b, W[3], gA,   act3);
    conv_mfma<2><<<MG, 256, 0, stream>>>(gA,  W[4], act3, act2);
    conv_mfma<2><<<MG, 256, 0, stream>>>(act3, W[5], act2, act1);
    l1bwd<<<DG, 256, 0, stream>>>(act2, c1r, c1i, grp);
  };

  auto run_gradf = [&](float* xp) {
    dft_row_planes<<<DFTG, DFTB, 0, stream>>>(xp, xp + P1, t1, EWf);
    dft_col_c<<<DFTG, DFTB, 0, stream>>>(t1, t2, EHf);
    mask2_kernel<<<NP1, 256, 0, stream>>>(t2, mask);
    dft_col_c<<<DFTG, DFTB, 0, stream>>>(t2, t1, EHi);
    dft_row_c<<<DFTG, DFTB, 0, stream>>>(t1, gf, EWi);
  };

  u16* WA[6] = {wp[0], wp[1], wp[2], wp[3], wp[4], wp[5]};
  u16* WB[6] = {wp[6], wp[7], wp[8], wp[9], wp[10], wp[11]};

  for (int ph = 0; ph < 3; ++ph) {
    run_gradr(x1p, cw[0], cw[1], WA, thr1);
    run_gradf(x1p);
    update_kernel<<<NP1, 256, 0, stream>>>(x1p, x1p+P1, gf, ct1, grp, grp+P1, al1, be1, ph);
    run_gradr(x2p, cw[8], cw[9], WB, thr2);
    run_gradf(x2p);
    update_kernel<<<NP1, 256, 0, stream>>>(x2p, x2p+P1, gf, ct2, grp, grp+P1, al2, be2, ph);
  }

  pack_kernel<<<NP1, 256, 0, stream>>>(x1p, x1p+P1, x2p, x2p+P1, out);
}

// Round 6
// 2838.307 us; speedup vs baseline: 20.9864x; 1.8125x over previous
//
#include <hip/hip_runtime.h>
#include <math.h>

#define HH 160
#define WW 180
#define HWSZ (HH*WW)
#define BB 8
#define P1 ((size_t)BB*HWSZ)            // 230400
#define PE ((size_t)BB*32*HWSZ)         // 7372800 (one 32-ch plane set)

typedef unsigned short u16;
typedef unsigned long long ull;
typedef __attribute__((ext_vector_type(8))) short short8;
typedef __attribute__((ext_vector_type(2))) unsigned long long ull2;
typedef __attribute__((ext_vector_type(4))) float floatx4;

// ---------------- bf16 helpers ----------------
__device__ __forceinline__ u16 f2b(float f) {
  unsigned u = __builtin_bit_cast(unsigned, f);
  unsigned r = (u + 0x7fffu + ((u >> 16) & 1u)) >> 16;
  return (u16)r;
}
__device__ __forceinline__ float b2f(u16 h) {
  return __builtin_bit_cast(float, ((unsigned)h) << 16);
}

// ---------------- activation (eq. 33), delta = 0.01 ----------------
__device__ __forceinline__ float actf(float x) {
  float q = x*x*25.0f + 0.5f*x + 0.0025f;
  float r = fmaxf(x, 0.0f);
  return (fabsf(x) > 0.01f) ? r : q;
}
__device__ __forceinline__ float actdf(float x) {
  float q = x*50.0f + 0.5f;
  float r = (x > 0.0f) ? 1.0f : 0.0f;
  return (fabsf(x) > 0.01f) ? r : q;
}

// ---------------- weight prep: fp32 [o][c][9] -> bf16 [tap][nt][plane(r,i,-i)][o16][c32]
__global__ void prep_w3(const float* __restrict__ wr, const float* __restrict__ wi,
                        u16* __restrict__ dst, int bwd) {
  int idx = blockIdx.x*256 + threadIdx.x;
  if (idx >= 9*32*32) return;
  int tap = idx >> 10; int rem = idx & 1023; int o = rem >> 5; int c = rem & 31;
  int s = bwd ? ((c*32 + o)*9 + (8 - tap)) : ((o*32 + c)*9 + tap);
  float vr = wr[s], vi = wi[s];
  int nt = o >> 4, m = o & 15;
  size_t base = ((((size_t)tap*2 + nt)*3)*16 + (size_t)m)*32 + c;
  dst[base]        = f2b(vr);
  dst[base + 512]  = f2b(vi);
  dst[base + 1024] = f2b(-vi);
}

// ---------------- MFMA complex conv 32->32, 3x3 SAME, implicit GEMM -----------------
// Activations are NHWC bf16: addr = ((b*HH+y)*WW+x)*32 + ch, R at 0, I at +PE.
// Tile: 48 wide x 4 high. 4 waves, wave wv -> output row y0+wv, 3 m-segments of 16 px.
// LDS stage: u16 [plane2][row6][col50][ch36pad]; epilogue fp32 via aliased LDS.
// MODE: 0 plain, 1 act, 2 complex-multiply by actdf(der planes)
template<int MODE>
__global__ __launch_bounds__(256)
void conv_mfma(const u16* __restrict__ inb, const u16* __restrict__ wb,
               u16* __restrict__ outb, const u16* __restrict__ derb)
{
  __shared__ alignas(16) char smraw[50688];
  u16*    stg = (u16*)smraw;      // [2][6][50][36] u16 = 43200 B
  float2* epi = (float2*)smraw;   // [4][48][33] float2 = 50688 B (aliased after sync)

  const int tid = threadIdx.x;
  const int lane = tid & 63, wv = tid >> 6;
  const int x0 = blockIdx.x * 48, y0 = blockIdx.y * 4, b = blockIdx.z;
  constexpr int PL = 6*50*36;     // u16 elements per plane in stage

  // ---- stage: 2400 16B chunks (plane,row,col,chq), fully coalesced NHWC reads ----
  for (int j = tid; j < 2400; j += 256) {
    int prow = j / 200; int rem = j - prow*200;
    int col = rem >> 2, chq = rem & 3;
    int plane = prow / 6, row = prow - plane*6;
    int gy = y0 - 1 + row, gx = x0 - 1 + col;
    ull v0 = 0, v1 = 0;
    if (gy >= 0 && gy < HH && gx >= 0 && gx < WW) {
      const ull* src = (const ull*)(inb + (size_t)plane*PE
                                    + (((size_t)b*HH + gy)*WW + gx)*32 + chq*8);
      v0 = src[0]; v1 = src[1];
    }
    ull* dst = (ull*)&stg[((size_t)prow*50 + col)*36 + chq*8];
    dst[0] = v0; dst[1] = v1;
  }
  __syncthreads();

  const int m = lane & 15, q = lane >> 4;

  floatx4 accr[3][2], acci[3][2];   // [seg][nt]
#pragma unroll
  for (int s = 0; s < 3; ++s)
#pragma unroll
    for (int nt = 0; nt < 2; ++nt) {
      accr[s][nt] = (floatx4){0.f,0.f,0.f,0.f};
      acci[s][nt] = (floatx4){0.f,0.f,0.f,0.f};
    }

#pragma unroll
  for (int tap = 0; tap < 9; ++tap) {
    const int ky = tap / 3, kx = tap - ky*3;
    short8 Ar[3], Ai[3];
#pragma unroll
    for (int s = 0; s < 3; ++s) {
      int cu = ((wv + ky)*50 + (s*16 + m + kx))*36 + q*8;    // 8B-aligned
      const ull* pR = (const ull*)&stg[cu];
      const ull* pI = (const ull*)&stg[cu + PL];
      ull2 vr; vr.x = pR[0]; vr.y = pR[1];
      ull2 vi; vi.x = pI[0]; vi.y = pI[1];
      Ar[s] = __builtin_bit_cast(short8, vr);
      Ai[s] = __builtin_bit_cast(short8, vi);
    }
#pragma unroll
    for (int nt = 0; nt < 2; ++nt) {
      const u16* pw = wb + ((size_t)(tap*2 + nt)*3)*512 + (size_t)m*32 + q*8;
      short8 Wr  = *(const short8*)pw;
      short8 Wi  = *(const short8*)(pw + 512);
      short8 nWi = *(const short8*)(pw + 1024);
#pragma unroll
      for (int s = 0; s < 3; ++s) {
        accr[s][nt] = __builtin_amdgcn_mfma_f32_16x16x32_bf16(Ar[s], Wr,  accr[s][nt], 0, 0, 0);
        accr[s][nt] = __builtin_amdgcn_mfma_f32_16x16x32_bf16(Ai[s], nWi, accr[s][nt], 0, 0, 0);
        acci[s][nt] = __builtin_amdgcn_mfma_f32_16x16x32_bf16(Ar[s], Wi,  acci[s][nt], 0, 0, 0);
        acci[s][nt] = __builtin_amdgcn_mfma_f32_16x16x32_bf16(Ai[s], Wr,  acci[s][nt], 0, 0, 0);
      }
    }
  }
  __syncthreads();   // all stage reads done; alias LDS as epi buffer

  // ---- epilogue spill: D layout col(lane&15)=och_lo, row(q*4+r)=px offset [R4/R5-verified]
#pragma unroll
  for (int s = 0; s < 3; ++s)
#pragma unroll
    for (int nt = 0; nt < 2; ++nt)
#pragma unroll
      for (int r = 0; r < 4; ++r) {
        int px = s*16 + q*4 + r;
        int och = nt*16 + m;
        epi[((size_t)wv*48 + px)*33 + och] = make_float2(accr[s][nt][r], acci[s][nt][r]);
      }
  __syncthreads();

  // ---- output pass: 96 jobs (4 rows x 24 px-pairs); lane = 2px x 32och, coalesced ----
  for (int j = wv; j < 96; j += 4) {
    int row = j / 24, pairi = j - row*24;
    int px = pairi*2 + (lane >> 5);
    int och = lane & 31;
    int x = x0 + px, y = y0 + row;
    if (x < WW) {
      float2 v = epi[((size_t)row*48 + px)*33 + och];
      float pr = v.x, pi = v.y;
      size_t gb = (((size_t)b*HH + y)*WW + x)*32 + och;
      if constexpr (MODE == 1) { pr = actf(pr); pi = actf(pi); }
      if constexpr (MODE == 2) {
        float dr = actdf(b2f(derb[gb]));
        float di = actdf(b2f(derb[PE + gb]));
        float nr = pr*dr - pi*di;
        pi = pr*di + pi*dr; pr = nr;
      }
      outb[gb]      = f2b(pr);
      outb[PE + gb] = f2b(pi);
    }
  }
}

// ---------------- layer-1 forward: complex conv 1->32 + act, fp32 planar in -> NHWC bf16
__global__ __launch_bounds__(256)
void l1fwd(const float* __restrict__ xp,   // R at 0, I at P1 (planar fp32)
           const float* __restrict__ wr, const float* __restrict__ wi,
           u16* __restrict__ outb)
{
  __shared__ float hR[10][34], hI[10][34];
  __shared__ float wt[9][32][2];
  const int tid = threadIdx.x;
  const int tx = tid & 31, ty = tid >> 5;
  const int x0 = blockIdx.x*32, y0 = blockIdx.y*8, b = blockIdx.z;

  for (int j = tid; j < 288; j += 256) {
    int o = j & 31, tap = j >> 5;
    wt[tap][o][0] = wr[o*9+tap]; wt[tap][o][1] = wi[o*9+tap];
  }
  for (int j = tid; j < 340; j += 256) {
    int yy = j / 34, xx = j - yy*34;
    int gy = y0 - 1 + yy, gx = x0 - 1 + xx;
    float vr = 0.f, vi = 0.f;
    if (gy >= 0 && gy < HH && gx >= 0 && gx < WW) {
      size_t o2 = (size_t)b*HWSZ + (size_t)gy*WW + gx;
      vr = xp[o2]; vi = xp[P1 + o2];
    }
    hR[yy][xx] = vr; hI[yy][xx] = vi;
  }
  __syncthreads();

  float accR[32], accI[32];
#pragma unroll
  for (int o = 0; o < 32; ++o) { accR[o] = 0.f; accI[o] = 0.f; }
#pragma unroll
  for (int tap = 0; tap < 9; ++tap) {
    int ky = tap/3, kx = tap - ky*3;
    float ar = hR[ty+ky][tx+kx], ai = hI[ty+ky][tx+kx];
#pragma unroll
    for (int o = 0; o < 32; ++o) {
      float wrv = wt[tap][o][0], wiv = wt[tap][o][1];
      accR[o] += ar*wrv - ai*wiv;
      accI[o] += ar*wiv + ai*wrv;
    }
  }
  int gx = x0 + tx, gy = y0 + ty;
  if (gx < WW) {
    size_t base = (((size_t)b*HH + gy)*WW + gx)*32;
    ull* dR = (ull*)(outb + base);
    ull* dI = (ull*)(outb + PE + base);
#pragma unroll
    for (int k = 0; k < 8; ++k) {
      ull vR = 0, vI = 0;
#pragma unroll
      for (int t = 0; t < 4; ++t) {
        vR |= (ull)f2b(actf(accR[k*4+t])) << (16*t);
        vI |= (ull)f2b(actf(accI[k*4+t])) << (16*t);
      }
      dR[k] = vR; dI[k] = vI;
    }
  }
}

// ---------------- layer-1 backward: complex convT 32->1, NHWC bf16 in -> fp32 planar ----
__global__ __launch_bounds__(256)
void l1bwd(const u16* __restrict__ gb,
           const float* __restrict__ wr, const float* __restrict__ wi,
           float* __restrict__ outp)    // R at 0, I at P1
{
  __shared__ u16 hR[8][10][34], hI[8][10][34];
  __shared__ float wt[32][9][2];
  const int tid = threadIdx.x;
  const int tx = tid & 31, ty = tid >> 5;
  const int x0 = blockIdx.x*32, y0 = blockIdx.y*8, b = blockIdx.z;

  for (int j = tid; j < 288; j += 256) {
    int c = j / 9, tap = j - c*9;
    wt[c][tap][0] = wr[c*9 + (8-tap)]; wt[c][tap][1] = wi[c*9 + (8-tap)];
  }

  float gr = 0.f, gi = 0.f;
  for (int c0 = 0; c0 < 32; c0 += 8) {
    __syncthreads();
    // stage: 680 16B NHWC chunks (2 planes x 340 positions), 8 ch each
    for (int j = tid; j < 680; j += 256) {
      int plane = j / 340; int rem = j - plane*340;
      int yy = rem / 34, xx = rem - yy*34;
      int gy = y0 - 1 + yy, gx = x0 - 1 + xx;
      ull v0 = 0, v1 = 0;
      if (gy >= 0 && gy < HH && gx >= 0 && gx < WW) {
        const ull* src = (const ull*)(gb + (size_t)plane*PE
                                      + (((size_t)b*HH + gy)*WW + gx)*32 + c0);
        v0 = src[0]; v1 = src[1];
      }
      u16* dst = plane ? &hI[0][yy][xx] : &hR[0][yy][xx];
#pragma unroll
      for (int t = 0; t < 4; ++t) dst[t*340]     = (u16)(v0 >> (16*t));
#pragma unroll
      for (int t = 0; t < 4; ++t) dst[(4+t)*340] = (u16)(v1 >> (16*t));
    }
    __syncthreads();
#pragma unroll 1
    for (int cc = 0; cc < 8; ++cc) {
#pragma unroll
      for (int tap = 0; tap < 9; ++tap) {
        int ky = tap/3, kx = tap - ky*3;
        float ar = b2f(hR[cc][ty+ky][tx+kx]);
        float ai = b2f(hI[cc][ty+ky][tx+kx]);
        float wrv = wt[c0+cc][tap][0], wiv = wt[c0+cc][tap][1];
        gr += ar*wrv - ai*wiv;
        gi += ar*wiv + ai*wrv;
      }
    }
  }
  int gx = x0 + tx, gy = y0 + ty;
  if (gx < WW) {
    size_t o2 = (size_t)b*HWSZ + (size_t)gy*WW + gx;
    outp[o2]      = gr;
    outp[P1 + o2] = gi;
  }
}

// ---------------- channel-norm normalize on NHWC bf16 planes ----------------
__global__ void normalize_b(u16* __restrict__ gb, const float* __restrict__ thr_p) {
  int i = blockIdx.x*256 + threadIdx.x;
  if (i >= (int)P1) return;
  float thr = thr_p[0];
  size_t base = (size_t)i * 32;
  const ull* pR = (const ull*)(gb + base);
  const ull* pI = (const ull*)(gb + PE + base);
  ull r[8], im[8];
#pragma unroll
  for (int k = 0; k < 8; ++k) { r[k] = pR[k]; im[k] = pI[k]; }
  float s = 0.f;
#pragma unroll
  for (int k = 0; k < 8; ++k)
#pragma unroll
    for (int t = 0; t < 4; ++t) {
      float vr = b2f((u16)(r[k] >> (16*t)));
      float vi = b2f((u16)(im[k] >> (16*t)));
      s += vr*vr + vi*vi;
    }
  float inv = 1.0f / fmaxf(sqrtf(s), thr);
  ull* oR = (ull*)(gb + base);
  ull* oI = (ull*)(gb + PE + base);
#pragma unroll
  for (int k = 0; k < 8; ++k) {
    ull nr = 0, ni = 0;
#pragma unroll
    for (int t = 0; t < 4; ++t) {
      nr |= (ull)f2b(b2f((u16)(r[k]  >> (16*t))) * inv) << (16*t);
      ni |= (ull)f2b(b2f((u16)(im[k] >> (16*t))) * inv) << (16*t);
    }
    oR[k] = nr; oI[k] = ni;
  }
}

// ---------------- DFT-by-matmul machinery (fp32) ----------------
__global__ void gen_dft(float2* __restrict__ M, int N, double sign, double scale) {
  int idx = blockIdx.x*256 + threadIdx.x;
  if (idx >= N*N) return;
  int r = idx / N, c = idx - r*N;
  long m = ((long)r * (long)c) % N;
  double a = sign * 2.0 * 3.14159265358979323846 * (double)m / (double)N;
  M[idx] = make_float2((float)(cos(a)*scale), (float)(sin(a)*scale));
}

__global__ void dft_row_planes(const float* __restrict__ xR, const float* __restrict__ xI,
                               float2* __restrict__ out, const float2* __restrict__ M) {
  int bh = blockIdx.x;
  int v = threadIdx.x; if (v >= WW) return;
  const float* rowR = xR + (size_t)bh*WW;
  const float* rowI = xI + (size_t)bh*WW;
  float ar = 0.f, ai = 0.f;
  for (int w = 0; w < WW; ++w) {
    float sr = rowR[w], si = rowI[w];
    float2 m = M[w*WW + v];
    ar += sr*m.x - si*m.y;
    ai += sr*m.y + si*m.x;
  }
  out[(size_t)bh*WW + v] = make_float2(ar, ai);
}

__global__ void dft_row_c(const float2* __restrict__ in, float2* __restrict__ out,
                          const float2* __restrict__ M) {
  int bh = blockIdx.x;
  int v = threadIdx.x; if (v >= WW) return;
  const float2* row = in + (size_t)bh*WW;
  float ar = 0.f, ai = 0.f;
  for (int w = 0; w < WW; ++w) {
    float2 s = row[w];
    float2 m = M[w*WW + v];
    ar += s.x*m.x - s.y*m.y;
    ai += s.x*m.y + s.y*m.x;
  }
  out[(size_t)bh*WW + v] = make_float2(ar, ai);
}

__global__ void dft_col_c(const float2* __restrict__ in, float2* __restrict__ out,
                          const float2* __restrict__ M) {
  int bu = blockIdx.x;
  int v = threadIdx.x; if (v >= WW) return;
  int b = bu / HH, u = bu - b*HH;
  const float2* base = in + (size_t)b*HWSZ;
  float ar = 0.f, ai = 0.f;
  for (int h = 0; h < HH; ++h) {
    float2 m = M[u*HH + h];
    float2 s = base[(size_t)h*WW + v];
    ar += s.x*m.x - s.y*m.y;
    ai += s.x*m.y + s.y*m.x;
  }
  out[(size_t)bu*WW + v] = make_float2(ar, ai);
}

// ---------------- small pointwise kernels (fp32) ----------------
__global__ void mask2_kernel(float2* __restrict__ t, const float* __restrict__ mask) {
  int i = blockIdx.x*256 + threadIdx.x;
  if (i >= (int)P1) return;
  float m = mask[i % HWSZ]; float mm = m*m;
  float2 v = t[i];
  t[i] = make_float2(v.x*mm, v.y*mm);
}

__global__ void maskk_kernel(const float* __restrict__ k, const float* __restrict__ mask,
                             float2* __restrict__ t) {
  int i = blockIdx.x*256 + threadIdx.x;
  if (i >= (int)P1) return;
  int b = i / HWSZ, p = i - b*HWSZ;
  float m = mask[p];
  t[i] = make_float2(m * k[(size_t)b*2*HWSZ + p], m * k[(size_t)b*2*HWSZ + HWSZ + p]);
}

__global__ void unpack_kernel(const float* __restrict__ x, float* __restrict__ xr,
                              float* __restrict__ xi) {
  int i = blockIdx.x*256 + threadIdx.x;
  if (i >= (int)P1) return;
  int b = i / HWSZ, p = i - b*HWSZ;
  xr[i] = x[(size_t)b*2*HWSZ + p];
  xi[i] = x[(size_t)b*2*HWSZ + HWSZ + p];
}

__global__ void update_kernel(float* __restrict__ xr, float* __restrict__ xi,
                              const float2* __restrict__ gradf, const float2* __restrict__ cterm,
                              const float* __restrict__ grR, const float* __restrict__ grI,
                              const float* __restrict__ alphas, const float* __restrict__ betas,
                              int phase) {
  int i = blockIdx.x*256 + threadIdx.x;
  if (i >= (int)P1) return;
  float a = alphas[phase], bb = betas[phase];
  float gfr = gradf[i].x - cterm[i].x;
  float gfi = gradf[i].y - cterm[i].y;
  xr[i] -= a*gfr + bb*grR[i];
  xi[i] -= a*gfi + bb*grI[i];
}

__global__ void pack_kernel(const float* __restrict__ x1r, const float* __restrict__ x1i,
                            const float* __restrict__ x2r, const float* __restrict__ x2i,
                            float* __restrict__ out) {
  int i = blockIdx.x*256 + threadIdx.x;
  if (i >= (int)P1) return;
  int b = i / HWSZ, p = i - b*HWSZ;
  size_t ob = (size_t)b*4*HWSZ;
  out[ob + p]          = x1r[i];
  out[ob + HWSZ + p]   = x1i[i];
  out[ob + 2*HWSZ + p] = x2r[i];
  out[ob + 3*HWSZ + p] = x2i[i];
}

// ---------------- launch ----------------
extern "C" void kernel_launch(void* const* d_in, const int* in_sizes, int n_in,
                              void* d_out, int out_size, void* d_ws, size_t ws_size,
                              hipStream_t stream) {
  (void)in_sizes; (void)n_in; (void)out_size; (void)ws_size;
  const float* x1in = (const float*)d_in[0];
  const float* x2in = (const float*)d_in[1];
  const float* k1   = (const float*)d_in[2];
  const float* k2   = (const float*)d_in[3];
  const float* mask = (const float*)d_in[4];
  const float* cw[16];
  for (int i = 0; i < 16; ++i) cw[i] = (const float*)d_in[5+i];
  const float* thr1 = (const float*)d_in[21];
  const float* thr2 = (const float*)d_in[22];
  const float* al1  = (const float*)d_in[23];
  const float* al2  = (const float*)d_in[24];
  const float* be1  = (const float*)d_in[25];
  const float* be2  = (const float*)d_in[26];
  float* out = (float*)d_out;

  // ---- workspace layout: bf16 region first, then fp32 region ----
  u16* U = (u16*)d_ws;
  size_t uoff = 0;
  auto alloc_u = [&](size_t n){ u16* p = U + uoff; uoff += (n + 15) & ~(size_t)15; return p; };
  u16* act1 = alloc_u(2*PE);
  u16* act2 = alloc_u(2*PE);
  u16* act3 = alloc_u(2*PE);
  u16* w4b  = alloc_u(2*PE);
  u16* gA   = alloc_u(2*PE);
  u16* wp[12];
  for (int i = 0; i < 12; ++i) wp[i] = alloc_u(27648);

  float* F = (float*)(U + uoff);
  size_t off = 0;
  auto alloc_f = [&](size_t n){ float* p = F + off; off += (n + 3) & ~(size_t)3; return p; };
  float* x1p = alloc_f(2*P1);
  float* x2p = alloc_f(2*P1);
  float* grp = alloc_f(2*P1);
  float2* t1  = (float2*)alloc_f(2*P1);
  float2* t2  = (float2*)alloc_f(2*P1);
  float2* gf  = (float2*)alloc_f(2*P1);
  float2* ct1 = (float2*)alloc_f(2*P1);
  float2* ct2 = (float2*)alloc_f(2*P1);
  float2* EWf = (float2*)alloc_f(2*(size_t)WW*WW);
  float2* EWi = (float2*)alloc_f(2*(size_t)WW*WW);
  float2* EHf = (float2*)alloc_f(2*(size_t)HH*HH);
  float2* EHi = (float2*)alloc_f(2*(size_t)HH*HH);

  const dim3 MG(4, 40, BB);       // mfma conv grid: 48x4 tiles
  const dim3 DG(6, 20, BB);       // direct conv grid: 32x8 tiles
  const int NP1 = (int)((P1 + 255)/256);
  const int DFTG = BB*HH;
  const int DFTB = 192;

  // twiddles
  gen_dft<<<(WW*WW+255)/256, 256, 0, stream>>>(EWf, WW, -1.0, 1.0);
  gen_dft<<<(WW*WW+255)/256, 256, 0, stream>>>(EWi, WW,  1.0, 1.0/(double)WW);
  gen_dft<<<(HH*HH+255)/256, 256, 0, stream>>>(EHf, HH, -1.0, 1.0);
  gen_dft<<<(HH*HH+255)/256, 256, 0, stream>>>(EHi, HH,  1.0, 1.0/(double)HH);

  // weight prep: branch A fwd L2,L3,L4 / bwd L4,L3,L2 ; branch B same (+6)
  prep_w3<<<36, 256, 0, stream>>>(cw[2],  cw[3],  wp[0], 0);
  prep_w3<<<36, 256, 0, stream>>>(cw[4],  cw[5],  wp[1], 0);
  prep_w3<<<36, 256, 0, stream>>>(cw[6],  cw[7],  wp[2], 0);
  prep_w3<<<36, 256, 0, stream>>>(cw[6],  cw[7],  wp[3], 1);
  prep_w3<<<36, 256, 0, stream>>>(cw[4],  cw[5],  wp[4], 1);
  prep_w3<<<36, 256, 0, stream>>>(cw[2],  cw[3],  wp[5], 1);
  prep_w3<<<36, 256, 0, stream>>>(cw[10], cw[11], wp[6], 0);
  prep_w3<<<36, 256, 0, stream>>>(cw[12], cw[13], wp[7], 0);
  prep_w3<<<36, 256, 0, stream>>>(cw[14], cw[15], wp[8], 0);
  prep_w3<<<36, 256, 0, stream>>>(cw[14], cw[15], wp[9], 1);
  prep_w3<<<36, 256, 0, stream>>>(cw[12], cw[13], wp[10], 1);
  prep_w3<<<36, 256, 0, stream>>>(cw[10], cw[11], wp[11], 1);

  // unpack x into fp32 planes
  unpack_kernel<<<NP1, 256, 0, stream>>>(x1in, x1p, x1p + P1);
  unpack_kernel<<<NP1, 256, 0, stream>>>(x2in, x2p, x2p + P1);

  // cterm = ifft2(mask * k) (phase-invariant)
  maskk_kernel<<<NP1, 256, 0, stream>>>(k1, mask, t1);
  dft_col_c<<<DFTG, DFTB, 0, stream>>>(t1, t2, EHi);
  dft_row_c<<<DFTG, DFTB, 0, stream>>>(t2, ct1, EWi);
  maskk_kernel<<<NP1, 256, 0, stream>>>(k2, mask, t1);
  dft_col_c<<<DFTG, DFTB, 0, stream>>>(t1, t2, EHi);
  dft_row_c<<<DFTG, DFTB, 0, stream>>>(t2, ct2, EWi);

  auto run_gradr = [&](float* xp, const float* c1r, const float* c1i,
                       u16* const* W, const float* thrp) {
    l1fwd<<<DG, 256, 0, stream>>>(xp, c1r, c1i, act1);
    conv_mfma<1><<<MG, 256, 0, stream>>>(act1, W[0], act2, nullptr);
    conv_mfma<1><<<MG, 256, 0, stream>>>(act2, W[1], act3, nullptr);
    conv_mfma<0><<<MG, 256, 0, stream>>>(act3, W[2], w4b, nullptr);
    normalize_b<<<NP1, 256, 0, stream>>>(w4b, thrp);
    conv_mfma<2><<<MG, 256, 0, stream>>>(w4b, W[3], gA,   act3);
    conv_mfma<2><<<MG, 256, 0, stream>>>(gA,  W[4], act3, act2);
    conv_mfma<2><<<MG, 256, 0, stream>>>(act3, W[5], act2, act1);
    l1bwd<<<DG, 256, 0, stream>>>(act2, c1r, c1i, grp);
  };

  auto run_gradf = [&](float* xp) {
    dft_row_planes<<<DFTG, DFTB, 0, stream>>>(xp, xp + P1, t1, EWf);
    dft_col_c<<<DFTG, DFTB, 0, stream>>>(t1, t2, EHf);
    mask2_kernel<<<NP1, 256, 0, stream>>>(t2, mask);
    dft_col_c<<<DFTG, DFTB, 0, stream>>>(t2, t1, EHi);
    dft_row_c<<<DFTG, DFTB, 0, stream>>>(t1, gf, EWi);
  };

  u16* WA[6] = {wp[0], wp[1], wp[2], wp[3], wp[4], wp[5]};
  u16* WB[6] = {wp[6], wp[7], wp[8], wp[9], wp[10], wp[11]};

  for (int ph = 0; ph < 3; ++ph) {
    run_gradr(x1p, cw[0], cw[1], WA, thr1);
    run_gradf(x1p);
    update_kernel<<<NP1, 256, 0, stream>>>(x1p, x1p+P1, gf, ct1, grp, grp+P1, al1, be1, ph);
    run_gradr(x2p, cw[8], cw[9], WB, thr2);
    run_gradf(x2p);
    update_kernel<<<NP1, 256, 0, stream>>>(x2p, x2p+P1, gf, ct2, grp, grp+P1, al2, be2, ph);
  }

  pack_kernel<<<NP1, 256, 0, stream>>>(x1p, x1p+P1, x2p, x2p+P1, out);
}

// Round 7
// 2217.593 us; speedup vs baseline: 26.8606x; 1.2799x over previous
//
#include <hip/hip_runtime.h>
#include <math.h>

#define HH 160
#define WW 180
#define HWSZ (HH*WW)
#define BB 8
#define BB2 16                           // both branches merged in z
#define P1 ((size_t)BB*HWSZ)             // 230400 (one branch, one plane)
#define PE2 ((size_t)BB2*32*HWSZ)        // merged 32-ch plane set (both branches)

typedef unsigned short u16;
typedef unsigned long long ull;
typedef __attribute__((ext_vector_type(8))) short short8;
typedef __attribute__((ext_vector_type(2))) unsigned long long ull2;
typedef __attribute__((ext_vector_type(4))) float floatx4;

struct Ptrs16 { const float* p[16]; };

// ---------------- bf16 helpers ----------------
__device__ __forceinline__ u16 f2b(float f) {
  unsigned u = __builtin_bit_cast(unsigned, f);
  unsigned r = (u + 0x7fffu + ((u >> 16) & 1u)) >> 16;
  return (u16)r;
}
__device__ __forceinline__ float b2f(u16 h) {
  return __builtin_bit_cast(float, ((unsigned)h) << 16);
}

// ---------------- activation (eq. 33), delta = 0.01 ----------------
__device__ __forceinline__ float actf(float x) {
  float q = x*x*25.0f + 0.5f*x + 0.0025f;
  float r = fmaxf(x, 0.0f);
  return (fabsf(x) > 0.01f) ? r : q;
}
__device__ __forceinline__ float actdf(float x) {
  float q = x*50.0f + 0.5f;
  float r = (x > 0.0f) ? 1.0f : 0.0f;
  return (fabsf(x) > 0.01f) ? r : q;
}

// ---------------- weight prep, all 12 slots in one dispatch ----------------
// fp32 [o][c][9] -> bf16 [tap][nt][plane(r,i,-i)][o16][c32], 27648 u16 per slot
__global__ void prep_all(Ptrs16 ps, u16* __restrict__ dst0) {
  const int rIdx[12] = {2,4,6,6,4,2,10,12,14,14,12,10};
  const int bwdF[12] = {0,0,0,1,1,1,0,0,0,1,1,1};
  int slot = blockIdx.x / 36;
  int idx = (blockIdx.x % 36)*256 + threadIdx.x;
  if (idx >= 9*32*32) return;
  const float* wr = ps.p[rIdx[slot]];
  const float* wi = ps.p[rIdx[slot]+1];
  u16* dst = dst0 + (size_t)slot*27648;
  int tap = idx >> 10; int rem = idx & 1023; int o = rem >> 5; int c = rem & 31;
  int s = bwdF[slot] ? ((c*32 + o)*9 + (8 - tap)) : ((o*32 + c)*9 + tap);
  float vr = wr[s], vi = wi[s];
  int nt = o >> 4, m = o & 15;
  size_t base = ((((size_t)tap*2 + nt)*3)*16 + (size_t)m)*32 + c;
  dst[base]        = f2b(vr);
  dst[base + 512]  = f2b(vi);
  dst[base + 1024] = f2b(-vi);
}

// ---------------- MFMA complex conv 32->32, 3x3 SAME, implicit GEMM -----------------
// NHWC bf16: addr = ((b*HH+y)*WW+x)*32 + ch, R at 0, I at +PE2. b in [0,16): branch=b>>3.
// Tile 48x4, 4 waves (wave=row), 3 m-segments. OPERAND-SWAPPED MFMA: A=weights (M=och),
// B=pixels (N=px) -> D row(q*4+r)=och, col(lane&15)=px -> direct 8B register stores.
// MODE: 0 plain, 1 act, 2 cmul by actdf(der), 3 channel-norm normalize (fused)
template<int MODE>
__global__ __launch_bounds__(256)
void conv_mfma(const u16* __restrict__ inb, const u16* __restrict__ wbA,
               const u16* __restrict__ wbB, u16* __restrict__ outb,
               const u16* __restrict__ derb,
               const float* __restrict__ thrA, const float* __restrict__ thrB)
{
  __shared__ alignas(16) u16 stg[2*6*50*36];   // 43200 B
  const int tid = threadIdx.x;
  const int lane = tid & 63, wv = tid >> 6;
  const int x0 = blockIdx.x * 48, y0 = blockIdx.y * 4, b = blockIdx.z;
  const u16* wb = (b < BB) ? wbA : wbB;
  constexpr int PL = 6*50*36;

  // ---- stage: 2400 16B chunks, fully coalesced NHWC reads ----
  for (int j = tid; j < 2400; j += 256) {
    int prow = j / 200; int rem = j - prow*200;
    int col = rem >> 2, chq = rem & 3;
    int plane = prow / 6, row = prow - plane*6;
    int gy = y0 - 1 + row, gx = x0 - 1 + col;
    ull v0 = 0, v1 = 0;
    if (gy >= 0 && gy < HH && gx >= 0 && gx < WW) {
      const ull* src = (const ull*)(inb + (size_t)plane*PE2
                                    + (((size_t)b*HH + gy)*WW + gx)*32 + chq*8);
      v0 = src[0]; v1 = src[1];
    }
    ull* dst = (ull*)&stg[(prow*50 + col)*36 + chq*8];
    dst[0] = v0; dst[1] = v1;
  }
  __syncthreads();

  const int m = lane & 15, q = lane >> 4;

  floatx4 accr[3][2], acci[3][2];   // [seg][nt]
#pragma unroll
  for (int s = 0; s < 3; ++s)
#pragma unroll
    for (int nt = 0; nt < 2; ++nt) {
      accr[s][nt] = (floatx4){0.f,0.f,0.f,0.f};
      acci[s][nt] = (floatx4){0.f,0.f,0.f,0.f};
    }

#pragma unroll
  for (int tap = 0; tap < 9; ++tap) {
    const int ky = tap / 3, kx = tap - ky*3;
    short8 Pr[3], Pi[3];     // pixel fragments: B[k=ch][n=px]
#pragma unroll
    for (int s = 0; s < 3; ++s) {
      int cu = ((wv + ky)*50 + (s*16 + m + kx))*36 + q*8;    // 8B-aligned
      const ull* pR = (const ull*)&stg[cu];
      const ull* pI = (const ull*)&stg[cu + PL];
      ull2 vr; vr.x = pR[0]; vr.y = pR[1];
      ull2 vi; vi.x = pI[0]; vi.y = pI[1];
      Pr[s] = __builtin_bit_cast(short8, vr);
      Pi[s] = __builtin_bit_cast(short8, vi);
    }
#pragma unroll
    for (int nt = 0; nt < 2; ++nt) {
      const u16* pw = wb + ((size_t)(tap*2 + nt)*3)*512 + (size_t)m*32 + q*8;
      short8 Wr  = *(const short8*)pw;          // weight frags: A[m=och][k=ch]
      short8 Wi  = *(const short8*)(pw + 512);
      short8 nWi = *(const short8*)(pw + 1024);
#pragma unroll
      for (int s = 0; s < 3; ++s) {
        accr[s][nt] = __builtin_amdgcn_mfma_f32_16x16x32_bf16(Wr,  Pr[s], accr[s][nt], 0, 0, 0);
        accr[s][nt] = __builtin_amdgcn_mfma_f32_16x16x32_bf16(nWi, Pi[s], accr[s][nt], 0, 0, 0);
        acci[s][nt] = __builtin_amdgcn_mfma_f32_16x16x32_bf16(Wr,  Pi[s], acci[s][nt], 0, 0, 0);
        acci[s][nt] = __builtin_amdgcn_mfma_f32_16x16x32_bf16(Wi,  Pr[s], acci[s][nt], 0, 0, 0);
      }
    }
  }

  // ---- direct epilogue: lane holds px = x0+s*16+m, och = nt*16+q*4+r in regs ----
  const int y = y0 + wv;
#pragma unroll
  for (int s = 0; s < 3; ++s) {
    int x = x0 + s*16 + m;
    bool ok = (x < WW);
    float invn = 1.0f;
    if constexpr (MODE == 3) {
      float ss = 0.f;
#pragma unroll
      for (int nt = 0; nt < 2; ++nt)
#pragma unroll
        for (int r = 0; r < 4; ++r)
          ss += accr[s][nt][r]*accr[s][nt][r] + acci[s][nt][r]*acci[s][nt][r];
      ss += __shfl_xor(ss, 16, 64);    // sum over q (lane bits 4,5): full 32-och norm
      ss += __shfl_xor(ss, 32, 64);
      float thr = (b < BB ? thrA : thrB)[0];
      invn = 1.0f / fmaxf(sqrtf(ss), thr);
    }
    size_t pxbase = (((size_t)b*HH + y)*WW + x)*32;
#pragma unroll
    for (int nt = 0; nt < 2; ++nt) {
      size_t gb = pxbase + nt*16 + q*4;
      ull dR = 0, dI = 0;
      if constexpr (MODE == 2) {
        if (ok) { dR = *(const ull*)(derb + gb); dI = *(const ull*)(derb + PE2 + gb); }
      }
      ull vR = 0, vI = 0;
#pragma unroll
      for (int r = 0; r < 4; ++r) {
        float pr = accr[s][nt][r], pi = acci[s][nt][r];
        if constexpr (MODE == 1) { pr = actf(pr); pi = actf(pi); }
        if constexpr (MODE == 3) { pr *= invn; pi *= invn; }
        if constexpr (MODE == 2) {
          float dr = actdf(b2f((u16)(dR >> (16*r))));
          float di = actdf(b2f((u16)(dI >> (16*r))));
          float nr = pr*dr - pi*di;
          pi = pr*di + pi*dr; pr = nr;
        }
        vR |= (ull)f2b(pr) << (16*r);
        vI |= (ull)f2b(pi) << (16*r);
      }
      if (ok) {
        *(ull*)(outb + gb)       = vR;
        *(ull*)(outb + PE2 + gb) = vI;
      }
    }
  }
}

// ---------------- layer-1 forward: complex conv 1->32 + act, planar fp32 -> NHWC bf16
// z in [0,16): branch = z>>3 selects weights and x-region
__global__ __launch_bounds__(256)
void l1fwd(const float* __restrict__ xall,
           const float* __restrict__ wrA, const float* __restrict__ wiA,
           const float* __restrict__ wrB, const float* __restrict__ wiB,
           u16* __restrict__ outb)
{
  __shared__ float hR[10][34], hI[10][34];
  __shared__ float wt[9][32][2];
  const int tid = threadIdx.x;
  const int tx = tid & 31, ty = tid >> 5;
  const int x0 = blockIdx.x*32, y0 = blockIdx.y*8, b = blockIdx.z;
  const int branch = b >> 3, img = b & 7;
  const float* wr = branch ? wrB : wrA;
  const float* wi = branch ? wiB : wiA;
  const float* xp = xall + (size_t)branch*2*P1 + (size_t)img*HWSZ;

  for (int j = tid; j < 288; j += 256) {
    int o = j & 31, tap = j >> 5;
    wt[tap][o][0] = wr[o*9+tap]; wt[tap][o][1] = wi[o*9+tap];
  }
  for (int j = tid; j < 340; j += 256) {
    int yy = j / 34, xx = j - yy*34;
    int gy = y0 - 1 + yy, gx = x0 - 1 + xx;
    float vr = 0.f, vi = 0.f;
    if (gy >= 0 && gy < HH && gx >= 0 && gx < WW) {
      size_t o2 = (size_t)gy*WW + gx;
      vr = xp[o2]; vi = xp[P1 + o2];
    }
    hR[yy][xx] = vr; hI[yy][xx] = vi;
  }
  __syncthreads();

  float accR[32], accI[32];
#pragma unroll
  for (int o = 0; o < 32; ++o) { accR[o] = 0.f; accI[o] = 0.f; }
#pragma unroll
  for (int tap = 0; tap < 9; ++tap) {
    int ky = tap/3, kx = tap - ky*3;
    float ar = hR[ty+ky][tx+kx], ai = hI[ty+ky][tx+kx];
#pragma unroll
    for (int o = 0; o < 32; ++o) {
      float wrv = wt[tap][o][0], wiv = wt[tap][o][1];
      accR[o] += ar*wrv - ai*wiv;
      accI[o] += ar*wiv + ai*wrv;
    }
  }
  int gx = x0 + tx, gy = y0 + ty;
  if (gx < WW) {
    size_t base = (((size_t)b*HH + gy)*WW + gx)*32;
    ull* dR = (ull*)(outb + base);
    ull* dI = (ull*)(outb + PE2 + base);
#pragma unroll
    for (int k = 0; k < 8; ++k) {
      ull vR = 0, vI = 0;
#pragma unroll
      for (int t = 0; t < 4; ++t) {
        vR |= (ull)f2b(actf(accR[k*4+t])) << (16*t);
        vI |= (ull)f2b(actf(accI[k*4+t])) << (16*t);
      }
      dR[k] = vR; dI[k] = vI;
    }
  }
}

// ---------------- layer-1 backward: complex convT 32->1, NHWC bf16 -> planar fp32 ----
__global__ __launch_bounds__(256)
void l1bwd(const u16* __restrict__ gb,
           const float* __restrict__ wrA, const float* __restrict__ wiA,
           const float* __restrict__ wrB, const float* __restrict__ wiB,
           float* __restrict__ outp)
{
  __shared__ u16 hR[8][10][34], hI[8][10][34];
  __shared__ float wt[32][9][2];
  const int tid = threadIdx.x;
  const int tx = tid & 31, ty = tid >> 5;
  const int x0 = blockIdx.x*32, y0 = blockIdx.y*8, b = blockIdx.z;
  const int branch = b >> 3, img = b & 7;
  const float* wr = branch ? wrB : wrA;
  const float* wi = branch ? wiB : wiA;

  for (int j = tid; j < 288; j += 256) {
    int c = j / 9, tap = j - c*9;
    wt[c][tap][0] = wr[c*9 + (8-tap)]; wt[c][tap][1] = wi[c*9 + (8-tap)];
  }

  float gr = 0.f, gi = 0.f;
  for (int c0 = 0; c0 < 32; c0 += 8) {
    __syncthreads();
    for (int j = tid; j < 680; j += 256) {
      int plane = j / 340; int rem = j - plane*340;
      int yy = rem / 34, xx = rem - yy*34;
      int gy = y0 - 1 + yy, gx = x0 - 1 + xx;
      ull v0 = 0, v1 = 0;
      if (gy >= 0 && gy < HH && gx >= 0 && gx < WW) {
        const ull* src = (const ull*)(gb + (size_t)plane*PE2
                                      + (((size_t)b*HH + gy)*WW + gx)*32 + c0);
        v0 = src[0]; v1 = src[1];
      }
      u16* dst = plane ? &hI[0][yy][xx] : &hR[0][yy][xx];
#pragma unroll
      for (int t = 0; t < 4; ++t) dst[t*340]     = (u16)(v0 >> (16*t));
#pragma unroll
      for (int t = 0; t < 4; ++t) dst[(4+t)*340] = (u16)(v1 >> (16*t));
    }
    __syncthreads();
#pragma unroll 1
    for (int cc = 0; cc < 8; ++cc) {
#pragma unroll
      for (int tap = 0; tap < 9; ++tap) {
        int ky = tap/3, kx = tap - ky*3;
        float ar = b2f(hR[cc][ty+ky][tx+kx]);
        float ai = b2f(hI[cc][ty+ky][tx+kx]);
        float wrv = wt[c0+cc][tap][0], wiv = wt[c0+cc][tap][1];
        gr += ar*wrv - ai*wiv;
        gi += ar*wiv + ai*wrv;
      }
    }
  }
  int gx = x0 + tx, gy = y0 + ty;
  if (gx < WW) {
    size_t o2 = (size_t)branch*2*P1 + (size_t)img*HWSZ + (size_t)gy*WW + gx;
    outp[o2]      = gr;
    outp[P1 + o2] = gi;
  }
}

// ---------------- DFT machinery ----------------
// one dispatch builds fwd ((cos,-sin)) and inv ((cos,sin)/N) matrices for size N
__global__ void gen_dft2(float2* __restrict__ Mf, float2* __restrict__ Mi, int N) {
  int idx = blockIdx.x*256 + threadIdx.x;
  if (idx >= N*N) return;
  int r = idx / N, c = idx - r*N;
  long mm = ((long)r * (long)c) % N;
  double a = 2.0 * 3.14159265358979323846 * (double)mm / (double)N;
  double cs = cos(a), sn = sin(a);
  Mf[idx] = make_float2((float)cs, (float)(-sn));
  Mi[idx] = make_float2((float)(cs/N), (float)(sn/N));
}

// row-DFT from planar x (both branches): bh over [0, 16*HH)
__global__ void dft_row_planes(const float* __restrict__ xall,
                               float2* __restrict__ out, const float2* __restrict__ M) {
  int bh = blockIdx.x;
  int v = threadIdx.x; if (v >= WW) return;
  int b2 = bh / HH, h = bh - b2*HH;
  int branch = b2 >> 3, img = b2 & 7;
  const float* rowR = xall + (size_t)branch*2*P1 + (size_t)img*HWSZ + (size_t)h*WW;
  const float* rowI = rowR + P1;
  float ar = 0.f, ai = 0.f;
  for (int w = 0; w < WW; ++w) {
    float sr = rowR[w], si = rowI[w];
    float2 m = M[w*WW + v];
    ar += sr*m.x - si*m.y;
    ai += sr*m.y + si*m.x;
  }
  out[(size_t)bh*WW + v] = make_float2(ar, ai);
}

__global__ void dft_row_c(const float2* __restrict__ in, float2* __restrict__ out,
                          const float2* __restrict__ M) {
  int bh = blockIdx.x;
  int v = threadIdx.x; if (v >= WW) return;
  const float2* row = in + (size_t)bh*WW;
  float ar = 0.f, ai = 0.f;
  for (int w = 0; w < WW; ++w) {
    float2 s = row[w];
    float2 m = M[w*WW + v];
    ar += s.x*m.x - s.y*m.y;
    ai += s.x*m.y + s.y*m.x;
  }
  out[(size_t)bh*WW + v] = make_float2(ar, ai);
}

__global__ void dft_col_c(const float2* __restrict__ in, float2* __restrict__ out,
                          const float2* __restrict__ M) {
  int bu = blockIdx.x;
  int v = threadIdx.x; if (v >= WW) return;
  int b = bu / HH, u = bu - b*HH;
  const float2* base = in + (size_t)b*HWSZ;
  float ar = 0.f, ai = 0.f;
  for (int h = 0; h < HH; ++h) {
    float2 m = M[u*HH + h];
    float2 s = base[(size_t)h*WW + v];
    ar += s.x*m.x - s.y*m.y;
    ai += s.x*m.y + s.y*m.x;
  }
  out[(size_t)bu*WW + v] = make_float2(ar, ai);
}

// col-iDFT with fused mask^2 on input element (h,v)
__global__ void dft_col_mask(const float2* __restrict__ in, float2* __restrict__ out,
                             const float2* __restrict__ M, const float* __restrict__ mask) {
  int bu = blockIdx.x;
  int v = threadIdx.x; if (v >= WW) return;
  int b = bu / HH, u = bu - b*HH;
  const float2* base = in + (size_t)b*HWSZ;
  float ar = 0.f, ai = 0.f;
  for (int h = 0; h < HH; ++h) {
    float mk = mask[h*WW + v]; float mm = mk*mk;
    float2 m = M[u*HH + h];
    float2 s = base[(size_t)h*WW + v];
    float sr = s.x*mm, si = s.y*mm;
    ar += sr*m.x - si*m.y;
    ai += sr*m.y + si*m.x;
  }
  out[(size_t)bu*WW + v] = make_float2(ar, ai);
}

// final row-iDFT fused with x update: x -= a*(gradf - ct) + bet*gr
__global__ void dft_row_update(const float2* __restrict__ in, const float2* __restrict__ M,
                               const float2* __restrict__ ctall, const float* __restrict__ grp,
                               float* __restrict__ xall,
                               const float* __restrict__ al1, const float* __restrict__ al2,
                               const float* __restrict__ be1, const float* __restrict__ be2,
                               int phase) {
  int bh = blockIdx.x;
  int v = threadIdx.x; if (v >= WW) return;
  int b2 = bh / HH, h = bh - b2*HH;
  int branch = b2 >> 3, img = b2 & 7;
  const float2* row = in + (size_t)bh*WW;
  float ar = 0.f, ai = 0.f;
  for (int w = 0; w < WW; ++w) {
    float2 s = row[w];
    float2 m = M[w*WW + v];
    ar += s.x*m.x - s.y*m.y;
    ai += s.x*m.y + s.y*m.x;
  }
  float2 ct = ctall[(size_t)bh*WW + v];
  float a   = (branch ? al2 : al1)[phase];
  float bet = (branch ? be2 : be1)[phase];
  size_t xo = (size_t)branch*2*P1 + (size_t)img*HWSZ + (size_t)h*WW + v;
  xall[xo]      -= a*(ar - ct.x) + bet*grp[xo];
  xall[P1 + xo] -= a*(ai - ct.y) + bet*grp[P1 + xo];
}

// ---------------- small pointwise kernels ----------------
__global__ void maskk_m(const float* __restrict__ k1, const float* __restrict__ k2,
                        const float* __restrict__ mask, float2* __restrict__ t) {
  int i = blockIdx.x*256 + threadIdx.x;
  if (i >= (int)(2*P1)) return;
  int branch = i >= (int)P1;
  int ii = i - branch*(int)P1;
  int b = ii / HWSZ, p = ii - b*HWSZ;
  const float* k = branch ? k2 : k1;
  float m = mask[p];
  t[i] = make_float2(m * k[(size_t)b*2*HWSZ + p], m * k[(size_t)b*2*HWSZ + HWSZ + p]);
}

__global__ void unpack_m(const float* __restrict__ x1, const float* __restrict__ x2,
                         float* __restrict__ xall) {
  int i = blockIdx.x*256 + threadIdx.x;
  if (i >= (int)(2*P1)) return;
  int branch = i >= (int)P1;
  int ii = i - branch*(int)P1;
  int b = ii / HWSZ, p = ii - b*HWSZ;
  const float* src = branch ? x2 : x1;
  size_t dst = (size_t)branch*2*P1 + (size_t)b*HWSZ + p;
  xall[dst]      = src[(size_t)b*2*HWSZ + p];
  xall[P1 + dst] = src[(size_t)b*2*HWSZ + HWSZ + p];
}

__global__ void pack_kernel(const float* __restrict__ xall, float* __restrict__ out) {
  int i = blockIdx.x*256 + threadIdx.x;
  if (i >= (int)P1) return;
  int b = i / HWSZ, p = i - b*HWSZ;
  size_t ob = (size_t)b*4*HWSZ;
  size_t x1o = (size_t)b*HWSZ + p;
  size_t x2o = 2*P1 + x1o;
  out[ob + p]          = xall[x1o];
  out[ob + HWSZ + p]   = xall[P1 + x1o];
  out[ob + 2*HWSZ + p] = xall[x2o];
  out[ob + 3*HWSZ + p] = xall[P1 + x2o];
}

// ---------------- launch ----------------
extern "C" void kernel_launch(void* const* d_in, const int* in_sizes, int n_in,
                              void* d_out, int out_size, void* d_ws, size_t ws_size,
                              hipStream_t stream) {
  (void)in_sizes; (void)n_in; (void)out_size; (void)ws_size;
  const float* x1in = (const float*)d_in[0];
  const float* x2in = (const float*)d_in[1];
  const float* k1   = (const float*)d_in[2];
  const float* k2   = (const float*)d_in[3];
  const float* mask = (const float*)d_in[4];
  Ptrs16 cw;
  for (int i = 0; i < 16; ++i) cw.p[i] = (const float*)d_in[5+i];
  const float* thr1 = (const float*)d_in[21];
  const float* thr2 = (const float*)d_in[22];
  const float* al1  = (const float*)d_in[23];
  const float* al2  = (const float*)d_in[24];
  const float* be1  = (const float*)d_in[25];
  const float* be2  = (const float*)d_in[26];
  float* out = (float*)d_out;

  // ---- workspace: bf16 region then fp32 region ----
  u16* U = (u16*)d_ws;
  size_t uoff = 0;
  auto alloc_u = [&](size_t n){ u16* p = U + uoff; uoff += (n + 15) & ~(size_t)15; return p; };
  u16* act1 = alloc_u(2*PE2);
  u16* act2 = alloc_u(2*PE2);
  u16* act3 = alloc_u(2*PE2);
  u16* w4b  = alloc_u(2*PE2);
  u16* wp0  = alloc_u(12*27648);

  float* F = (float*)(U + uoff);
  size_t off = 0;
  auto alloc_f = [&](size_t n){ float* p = F + off; off += (n + 3) & ~(size_t)3; return p; };
  float*  xall = alloc_f(4*P1);                       // [branch][plane][P1]
  float*  grp  = alloc_f(4*P1);
  float2* t1   = (float2*)alloc_f(4*P1);              // [16][HWSZ] complex
  float2* t2   = (float2*)alloc_f(4*P1);
  float2* ctall= (float2*)alloc_f(4*P1);
  float2* EWf  = (float2*)alloc_f(2*(size_t)WW*WW);
  float2* EWi  = (float2*)alloc_f(2*(size_t)WW*WW);
  float2* EHf  = (float2*)alloc_f(2*(size_t)HH*HH);
  float2* EHi  = (float2*)alloc_f(2*(size_t)HH*HH);

  const dim3 MG(4, 40, BB2);      // conv: 48x4 tiles, both branches
  const dim3 DG(6, 20, BB2);      // l1 convs
  const int NP1 = (int)((P1 + 255)/256);
  const int NP2 = (int)((2*P1 + 255)/256);
  const int DFTG = BB2*HH;        // 2560
  const int DFTB = 192;

  gen_dft2<<<(WW*WW+255)/256, 256, 0, stream>>>(EWf, EWi, WW);
  gen_dft2<<<(HH*HH+255)/256, 256, 0, stream>>>(EHf, EHi, HH);
  prep_all<<<12*36, 256, 0, stream>>>(cw, wp0);
  unpack_m<<<NP2, 256, 0, stream>>>(x1in, x2in, xall);

  // cterm = ifft2(mask*k), both branches
  maskk_m<<<NP2, 256, 0, stream>>>(k1, k2, mask, t1);
  dft_col_c<<<DFTG, DFTB, 0, stream>>>(t1, t2, EHi);
  dft_row_c<<<DFTG, DFTB, 0, stream>>>(t2, ctall, EWi);

  u16* WA[6]; u16* WB[6];
  for (int i = 0; i < 6; ++i) { WA[i] = wp0 + (size_t)i*27648; WB[i] = wp0 + (size_t)(6+i)*27648; }

  for (int ph = 0; ph < 3; ++ph) {
    // grad_r both branches
    l1fwd<<<DG, 256, 0, stream>>>(xall, cw.p[0], cw.p[1], cw.p[8], cw.p[9], act1);
    conv_mfma<1><<<MG, 256, 0, stream>>>(act1, WA[0], WB[0], act2, nullptr, nullptr, nullptr);
    conv_mfma<1><<<MG, 256, 0, stream>>>(act2, WA[1], WB[1], act3, nullptr, nullptr, nullptr);
    conv_mfma<3><<<MG, 256, 0, stream>>>(act3, WA[2], WB[2], w4b, nullptr, thr1, thr2);
    conv_mfma<2><<<MG, 256, 0, stream>>>(w4b,  WA[3], WB[3], act3, act3, nullptr, nullptr);
    conv_mfma<2><<<MG, 256, 0, stream>>>(act3, WA[4], WB[4], act2, act2, nullptr, nullptr);
    conv_mfma<2><<<MG, 256, 0, stream>>>(act2, WA[5], WB[5], act1, act1, nullptr, nullptr);
    l1bwd<<<DG, 256, 0, stream>>>(act1, cw.p[0], cw.p[1], cw.p[8], cw.p[9], grp);
    // grad_f both branches + fused update
    dft_row_planes<<<DFTG, DFTB, 0, stream>>>(xall, t1, EWf);
    dft_col_c<<<DFTG, DFTB, 0, stream>>>(t1, t2, EHf);
    dft_col_mask<<<DFTG, DFTB, 0, stream>>>(t2, t1, EHi, mask);
    dft_row_update<<<DFTG, DFTB, 0, stream>>>(t1, EWi, ctall, grp, xall,
                                              al1, al2, be1, be2, ph);
  }

  pack_kernel<<<NP1, 256, 0, stream>>>(xall, out);
}